// Round 3
// baseline (609.523 us; speedup 1.0000x reference)
//
#include <hip/hip_runtime.h>
#include <stdint.h>

// Problem dims
#define Bdim 32
#define Ndim 4096
#define Cin  64
#define Cout 64
#define Demb 16

typedef __bf16 bf16x8 __attribute__((ext_vector_type(8)));
typedef float  f32x4  __attribute__((ext_vector_type(4)));

#define GLOBAL_AS(p) ((__attribute__((address_space(1))) void*)(p))
#define LDS_AS(p)    ((__attribute__((address_space(3))) void*)(p))

__device__ __forceinline__ uint16_t f2bf(float x) {
    union { float f; uint32_t u; } v; v.f = x;
    uint32_t r = v.u + 0x7FFFu + ((v.u >> 16) & 1u);   // RNE, finite inputs
    return (uint16_t)(r >> 16);
}

__device__ __forceinline__ bf16x8 pack8(float4 a, float4 b) {
    union { uint16_t u[8]; bf16x8 v; } r;
    r.u[0] = f2bf(a.x); r.u[1] = f2bf(a.y); r.u[2] = f2bf(a.z); r.u[3] = f2bf(a.w);
    r.u[4] = f2bf(b.x); r.u[5] = f2bf(b.y); r.u[6] = f2bf(b.z); r.u[7] = f2bf(b.w);
    return r.v;
}

// ---------------------------------------------------------------------------
// K1: A[n][m] = softmax_m(relu(E[n]·E[m])), bf16 out.  grid 256, block 256.
// ---------------------------------------------------------------------------
__global__ __launch_bounds__(256) void k1_dyn_adj(const float* __restrict__ E,
                                                  uint16_t* __restrict__ A) {
    const int t = threadIdx.x;
    const int n0 = blockIdx.x * 16;
    __shared__ float Er_s[16][16];
    __shared__ float red_s[4];
    __shared__ float inv_s[8];

    Er_s[t >> 4][t & 15] = E[(n0 + (t >> 4)) * Demb + (t & 15)];
    __syncthreads();

    for (int half = 0; half < 2; ++half) {
        float er[8][16];
#pragma unroll
        for (int r = 0; r < 8; ++r)
#pragma unroll
            for (int d = 0; d < 16; ++d) er[r][d] = Er_s[half * 8 + r][d];

        float sacc[8];
#pragma unroll
        for (int r = 0; r < 8; ++r) sacc[r] = 0.f;

        for (int c = 0; c < 16; ++c) {
            const int m = c * 256 + t;
            const float4* ep = (const float4*)(E + (size_t)m * Demb);
            float4 e0 = ep[0], e1 = ep[1], e2 = ep[2], e3 = ep[3];
            float em[16] = {e0.x, e0.y, e0.z, e0.w, e1.x, e1.y, e1.z, e1.w,
                            e2.x, e2.y, e2.z, e2.w, e3.x, e3.y, e3.z, e3.w};
#pragma unroll
            for (int r = 0; r < 8; ++r) {
                float v = 0.f;
#pragma unroll
                for (int d = 0; d < 16; ++d) v = fmaf(er[r][d], em[d], v);
                v = fmaxf(v, 0.f);
                sacc[r] += __expf(v);
            }
        }
#pragma unroll
        for (int r = 0; r < 8; ++r) {
            float s = sacc[r];
#pragma unroll
            for (int off = 32; off > 0; off >>= 1) s += __shfl_down(s, off, 64);
            __syncthreads();
            if ((t & 63) == 0) red_s[t >> 6] = s;
            __syncthreads();
            if (t == 0) inv_s[r] = 1.f / (red_s[0] + red_s[1] + red_s[2] + red_s[3]);
        }
        __syncthreads();
        float inv[8];
#pragma unroll
        for (int r = 0; r < 8; ++r) inv[r] = inv_s[r];

        for (int c = 0; c < 16; ++c) {
            const int m = c * 256 + t;
            const float4* ep = (const float4*)(E + (size_t)m * Demb);
            float4 e0 = ep[0], e1 = ep[1], e2 = ep[2], e3 = ep[3];
            float em[16] = {e0.x, e0.y, e0.z, e0.w, e1.x, e1.y, e1.z, e1.w,
                            e2.x, e2.y, e2.z, e2.w, e3.x, e3.y, e3.z, e3.w};
#pragma unroll
            for (int r = 0; r < 8; ++r) {
                float v = 0.f;
#pragma unroll
                for (int d = 0; d < 16; ++d) v = fmaf(er[r][d], em[d], v);
                v = fmaxf(v, 0.f);
                A[(size_t)(n0 + half * 8 + r) * Ndim + m] = f2bf(__expf(v) * inv[r]);
            }
        }
        __syncthreads();
    }
}

// ---------------------------------------------------------------------------
// K2: Xtt[j = b*64+c][m] = bf16(x[b][m][c]).  grid (64 mtiles, 32 b), 256 thr.
// ---------------------------------------------------------------------------
__global__ __launch_bounds__(256) void k2_transpose(const float* __restrict__ x,
                                                    uint16_t* __restrict__ Xtt) {
    __shared__ __align__(16) uint16_t T[64][72];
    const int t = threadIdx.x;
    const int m0 = blockIdx.x * 64;
    const int b = blockIdx.y;
    const int c = t & 63;
#pragma unroll
    for (int j = 0; j < 16; ++j) {
        const int m = (t >> 6) + j * 4;
        T[c][m] = f2bf(x[((size_t)b * Ndim + (m0 + m)) * Cin + c]);
    }
    __syncthreads();
    const int c2 = t >> 2, mo = (t & 3) * 16;
    const uint4* src = (const uint4*)&T[c2][mo];
    uint4 v0 = src[0], v1 = src[1];
    uint4* dst = (uint4*)(Xtt + (size_t)(b * Cin + c2) * Ndim + m0 + mo);
    dst[0] = v0;
    dst[1] = v1;
}

// ---------------------------------------------------------------------------
// K3: XG[n][j] = sum_m A[n][m] * Xtt[j][m]   (4096 x 2048 x 4096, bf16)
// ---------------------------------------------------------------------------
#define GK 4096
#define GN 2048
__global__ __launch_bounds__(256) void k3_gemm(const uint16_t* __restrict__ Abf,
                                               const uint16_t* __restrict__ Bbf,
                                               uint16_t* __restrict__ Cbf) {
    __shared__ __align__(16) uint16_t As[128 * 32];
    __shared__ __align__(16) uint16_t Bs[128 * 32];
    const int t = threadIdx.x;
    const int lane = t & 63;
    const int w = t >> 6;
    const int wr = w >> 1, wc = w & 1;
    const int bm = blockIdx.y * 128;
    const int bn = blockIdx.x * 128;

    f32x4 acc[4][4];
#pragma unroll
    for (int i = 0; i < 4; ++i)
#pragma unroll
        for (int j = 0; j < 4; ++j) acc[i][j] = (f32x4){0.f, 0.f, 0.f, 0.f};

    const uint16_t* agp[2];
    const uint16_t* bgp[2];
    uint16_t* alp[2];
    uint16_t* blp[2];
#pragma unroll
    for (int i = 0; i < 2; ++i) {
        const int r = w * 32 + i * 16 + (lane >> 2);
        const int cg = (lane & 3) ^ ((r >> 1) & 3);
        agp[i] = Abf + (size_t)(bm + r) * GK + cg * 8;
        bgp[i] = Bbf + (size_t)(bn + r) * GK + cg * 8;
        alp[i] = &As[(w * 32 + i * 16) * 32];
        blp[i] = &Bs[(w * 32 + i * 16) * 32];
    }

    int offA[4], offB[4];
#pragma unroll
    for (int i = 0; i < 4; ++i) {
        const int m = wr * 64 + i * 16 + (lane & 15);
        offA[i] = m * 32 + (((lane >> 4) ^ ((m >> 1) & 3)) * 8);
        const int n = wc * 64 + i * 16 + (lane & 15);
        offB[i] = n * 32 + (((lane >> 4) ^ ((n >> 1) & 3)) * 8);
    }

    for (int kt = 0; kt < GK / 32; ++kt) {
#pragma unroll
        for (int i = 0; i < 2; ++i) {
            __builtin_amdgcn_global_load_lds(GLOBAL_AS(agp[i] + (size_t)kt * 32), LDS_AS(alp[i]), 16, 0, 0);
            __builtin_amdgcn_global_load_lds(GLOBAL_AS(bgp[i] + (size_t)kt * 32), LDS_AS(blp[i]), 16, 0, 0);
        }
        __syncthreads();
        bf16x8 af[4], bfr[4];
#pragma unroll
        for (int i = 0; i < 4; ++i) {
            af[i] = *(const bf16x8*)(As + offA[i]);
            bfr[i] = *(const bf16x8*)(Bs + offB[i]);
        }
#pragma unroll
        for (int i = 0; i < 4; ++i)
#pragma unroll
            for (int j = 0; j < 4; ++j)
                acc[i][j] = __builtin_amdgcn_mfma_f32_16x16x32_bf16(af[i], bfr[j], acc[i][j], 0, 0, 0);
        __syncthreads();
    }
#pragma unroll
    for (int i = 0; i < 4; ++i)
#pragma unroll
        for (int j = 0; j < 4; ++j)
#pragma unroll
            for (int r = 0; r < 4; ++r) {
                const int row = bm + wr * 64 + i * 16 + (lane >> 4) * 4 + r;
                const int col = bn + wc * 64 + j * 16 + (lane & 15);
                Cbf[(size_t)row * GN + col] = f2bf(acc[i][j][r]);
            }
}

// ---------------------------------------------------------------------------
// K4a: sd[n] = sqrt(1/(rowsum(adj[n]) + 0.5)); also zero `scale`.
// ---------------------------------------------------------------------------
__global__ __launch_bounds__(256) void k4a_rowsum(const float* __restrict__ adj,
                                                  float* __restrict__ sd,
                                                  float* __restrict__ scale) {
    const int t = threadIdx.x;
    const int n = blockIdx.x;
    const int gid = blockIdx.x * 256 + t;
    if (gid < Ndim) scale[gid] = 0.f;
    __shared__ float red_s[4];
    const float4* ap = (const float4*)(adj + (size_t)n * Ndim);
    float s = 0.f;
#pragma unroll
    for (int q = 0; q < 4; ++q) {
        float4 a = ap[q * 256 + t];
        s += a.x + a.y + a.z + a.w;
    }
#pragma unroll
    for (int off = 32; off > 0; off >>= 1) s += __shfl_down(s, off, 64);
    if ((t & 63) == 0) red_s[t >> 6] = s;
    __syncthreads();
    if (t == 0) sd[n] = sqrtf(1.f / (red_s[0] + red_s[1] + red_s[2] + red_s[3] + 0.5f));
}

__device__ __forceinline__ float block_reduce(float v, float* red_s, int t, bool domax) {
#pragma unroll
    for (int off = 32; off > 0; off >>= 1) {
        float o = __shfl_down(v, off, 64);
        v = domax ? fmaxf(v, o) : (v + o);
    }
    __syncthreads();
    if ((t & 63) == 0) red_s[t >> 6] = v;
    __syncthreads();
    return domax ? fmaxf(fmaxf(red_s[0], red_s[1]), fmaxf(red_s[2], red_s[3]))
                 : (red_s[0] + red_s[1] + red_s[2] + red_s[3]);
}

// ---------------------------------------------------------------------------
// K4b: scale[m] = sum_n softmax_row(softmax_row(sd*(adj+0.5I)*sd))[n][m]
// ---------------------------------------------------------------------------
__global__ __launch_bounds__(256) void k4b_scale(const float* __restrict__ adj,
                                                 const float* __restrict__ sd,
                                                 float* __restrict__ scale) {
    const int t = threadIdx.x;
    const int nb = blockIdx.x * 16;
    __shared__ float red_s[4];
    float sdm[16], colsum[16];
#pragma unroll
    for (int q = 0; q < 4; ++q) {
        float4 v = *(const float4*)(sd + q * 1024 + t * 4);
        sdm[q * 4 + 0] = v.x; sdm[q * 4 + 1] = v.y;
        sdm[q * 4 + 2] = v.z; sdm[q * 4 + 3] = v.w;
        colsum[q * 4 + 0] = colsum[q * 4 + 1] = colsum[q * 4 + 2] = colsum[q * 4 + 3] = 0.f;
    }
    for (int r = 0; r < 16; ++r) {
        const int n = nb + r;
        const float sdn = sd[n];
        float v[16];
#pragma unroll
        for (int q = 0; q < 4; ++q) {
            float4 a = *(const float4*)(adj + (size_t)n * Ndim + q * 1024 + t * 4);
            const int mb = q * 1024 + t * 4;
            v[q * 4 + 0] = a.x + ((mb + 0) == n ? 0.5f : 0.f);
            v[q * 4 + 1] = a.y + ((mb + 1) == n ? 0.5f : 0.f);
            v[q * 4 + 2] = a.z + ((mb + 2) == n ? 0.5f : 0.f);
            v[q * 4 + 3] = a.w + ((mb + 3) == n ? 0.5f : 0.f);
        }
        float mx = -1e30f;
#pragma unroll
        for (int i = 0; i < 16; ++i) { v[i] = sdn * v[i] * sdm[i]; mx = fmaxf(mx, v[i]); }
        mx = block_reduce(mx, red_s, t, true);
        float s1 = 0.f;
#pragma unroll
        for (int i = 0; i < 16; ++i) { v[i] = __expf(v[i] - mx); s1 += v[i]; }
        s1 = block_reduce(s1, red_s, t, false);
        const float inv1 = 1.f / s1;
        float s2 = 0.f;
#pragma unroll
        for (int i = 0; i < 16; ++i) { v[i] = __expf(v[i] * inv1); s2 += v[i]; }
        s2 = block_reduce(s2, red_s, t, false);
        const float inv2 = 1.f / s2;
#pragma unroll
        for (int i = 0; i < 16; ++i) colsum[i] += v[i] * inv2;
    }
#pragma unroll
    for (int q = 0; q < 4; ++q)
#pragma unroll
        for (int u = 0; u < 4; ++u)
            atomicAdd(scale + q * 1024 + t * 4 + u, colsum[q * 4 + u]);
}

// ---------------------------------------------------------------------------
// K5 (coalesced rewrite): Wt[n][o][ki] = bf16(sum_d E[n,d]*pool[d][ki][o]).
// Thread t, pass it owns elements e = it*2048 + t*8 .. +8 of each node's
// contiguous 8192-elem row (o = e>>7, ki = e&127) -> wave writes 1 KB runs,
// full-line coalesced.  4 nodes/block (E rows broadcast from LDS, acc = 32
// regs), grid 1024 -> 16 waves/CU avg to hide the scalar L2-hit pool reads.
// ---------------------------------------------------------------------------
__global__ __launch_bounds__(256) void k5_wgen(const float* __restrict__ E,
                                               const float* __restrict__ pool,
                                               const float* __restrict__ bias_pool,
                                               uint16_t* __restrict__ Wt,
                                               float* __restrict__ biasn) {
    const int t = threadIdx.x;
    const int n0 = blockIdx.x * 4;
    __shared__ float En[4][16];
    if (t < 64) En[t >> 4][t & 15] = E[(n0 + (t >> 4)) * Demb + (t & 15)];
    __syncthreads();
    const int ki0 = (t & 15) * 8;
    const int ob = t >> 4;
#pragma unroll
    for (int it = 0; it < 4; ++it) {
        const int o = it * 16 + ob;
        float acc[4][8];
#pragma unroll
        for (int g = 0; g < 4; ++g)
#pragma unroll
            for (int j = 0; j < 8; ++j) acc[g][j] = 0.f;
#pragma unroll 4
        for (int d = 0; d < 16; ++d) {
            float p[8];
#pragma unroll
            for (int j = 0; j < 8; ++j) p[j] = pool[d * 8192 + (ki0 + j) * 64 + o];
#pragma unroll
            for (int g = 0; g < 4; ++g) {
                const float e = En[g][d];
#pragma unroll
                for (int j = 0; j < 8; ++j) acc[g][j] = fmaf(e, p[j], acc[g][j]);
            }
        }
#pragma unroll
        for (int g = 0; g < 4; ++g) {
            union { uint16_t u[8]; uint4 v; } r;
#pragma unroll
            for (int j = 0; j < 8; ++j) r.u[j] = f2bf(acc[g][j]);
            *(uint4*)(Wt + (size_t)(n0 + g) * 8192 + it * 2048 + t * 8) = r.v;
        }
    }
    if (t < 64) {
        for (int g = 0; g < 4; ++g) {
            float a = 0.f;
#pragma unroll
            for (int d = 0; d < 16; ++d) a += En[g][d] * bias_pool[d * 64 + t];
            biasn[(size_t)(n0 + g) * 64 + t] = a;
        }
    }
}

// ---------------------------------------------------------------------------
// K6 (MFMA): one wave per node n.  See round-1 notes.
// ---------------------------------------------------------------------------
__global__ __launch_bounds__(256) void k6_gconv(const float* __restrict__ x,
                                                const uint16_t* __restrict__ XG,
                                                const uint16_t* __restrict__ Wt,
                                                const float* __restrict__ biasn,
                                                const float* __restrict__ scale,
                                                const float* __restrict__ lin_w,
                                                const float* __restrict__ lin_b,
                                                float* __restrict__ out) {
    __shared__ __align__(16) uint16_t Ws[4][64][136];
    __shared__ __align__(16) uint16_t Lws[64][72];
    const int t = threadIdx.x;
    const int n0 = blockIdx.x * 4;

#pragma unroll
    for (int j = 0; j < 16; ++j) {
        const int e8 = (j * 256 + t) * 8;
        const int g = e8 >> 13;
        const int r = e8 & 8191;
        uint4 v = *(const uint4*)(Wt + (size_t)(n0 + g) * 8192 + r);
        *(uint4*)&Ws[g][r >> 7][r & 127] = v;
    }
    {
        const int o = t >> 2, i0 = (t & 3) * 16;
        const float4* lp = (const float4*)(lin_w + o * 64 + i0);
        float4 a0 = lp[0], a1 = lp[1], a2 = lp[2], a3 = lp[3];
        union { uint16_t u[16]; uint4 v[2]; } r;
        r.u[0] = f2bf(a0.x); r.u[1] = f2bf(a0.y); r.u[2]  = f2bf(a0.z); r.u[3]  = f2bf(a0.w);
        r.u[4] = f2bf(a1.x); r.u[5] = f2bf(a1.y); r.u[6]  = f2bf(a1.z); r.u[7]  = f2bf(a1.w);
        r.u[8] = f2bf(a2.x); r.u[9] = f2bf(a2.y); r.u[10] = f2bf(a2.z); r.u[11] = f2bf(a2.w);
        r.u[12] = f2bf(a3.x); r.u[13] = f2bf(a3.y); r.u[14] = f2bf(a3.z); r.u[15] = f2bf(a3.w);
        *(uint4*)&Lws[o][i0] = r.v[0];
        *(uint4*)&Lws[o][i0 + 8] = r.v[1];
    }

    const int w = t >> 6, lane = t & 63;
    const int n = n0 + w;
    const int l15 = lane & 15;
    const int q8 = (lane >> 4) * 8;

    bf16x8 a[2][4];
#pragma unroll
    for (int mt = 0; mt < 2; ++mt) {
        const int b = mt * 16 + l15;
        const float* xp = x + ((size_t)b * Ndim + n) * 64 + q8;
        a[mt][0] = pack8(((const float4*)xp)[0], ((const float4*)xp)[1]);
        a[mt][1] = pack8(((const float4*)(xp + 32))[0], ((const float4*)(xp + 32))[1]);
        const uint16_t* gp = XG + (size_t)n * 2048 + b * 64 + q8;
        a[mt][2] = *(const bf16x8*)gp;
        a[mt][3] = *(const bf16x8*)(gp + 32);
    }

    f32x4 accg[2][4], accs[2][4];
#pragma unroll
    for (int mt = 0; mt < 2; ++mt)
#pragma unroll
        for (int j = 0; j < 4; ++j) {
            accg[mt][j] = (f32x4){0.f, 0.f, 0.f, 0.f};
            accs[mt][j] = (f32x4){0.f, 0.f, 0.f, 0.f};
        }

    __syncthreads();

#pragma unroll
    for (int ks = 0; ks < 4; ++ks) {
        bf16x8 bw[4];
#pragma unroll
        for (int j = 0; j < 4; ++j)
            bw[j] = *(const bf16x8*)&Ws[w][j * 16 + l15][ks * 32 + q8];
#pragma unroll
        for (int mt = 0; mt < 2; ++mt)
#pragma unroll
            for (int j = 0; j < 4; ++j)
                accg[mt][j] = __builtin_amdgcn_mfma_f32_16x16x32_bf16(a[mt][ks], bw[j], accg[mt][j], 0, 0, 0);
        if (ks < 2) {
            bf16x8 bl[4];
#pragma unroll
            for (int j = 0; j < 4; ++j)
                bl[j] = *(const bf16x8*)&Lws[j * 16 + l15][ks * 32 + q8];
#pragma unroll
            for (int mt = 0; mt < 2; ++mt)
#pragma unroll
                for (int j = 0; j < 4; ++j)
                    accs[mt][j] = __builtin_amdgcn_mfma_f32_16x16x32_bf16(a[mt][ks], bl[j], accs[mt][j], 0, 0, 0);
        }
    }

    const float sc = scale[n];
#pragma unroll
    for (int j = 0; j < 4; ++j) {
        const int o = j * 16 + l15;
        const float bn = biasn[(size_t)n * 64 + o];
        const float lb = lin_b[o];
#pragma unroll
        for (int mt = 0; mt < 2; ++mt)
#pragma unroll
            for (int r = 0; r < 4; ++r) {
                const int b = mt * 16 + (lane >> 4) * 4 + r;
                const float gg = accg[mt][j][r] + bn;
                const float xs = sc * accs[mt][j][r] + lb;
                out[((size_t)b * Ndim + n) * 64 + o] = gg + xs / (1.f + __expf(-xs));
            }
    }
}

// ---------------------------------------------------------------------------
extern "C" void kernel_launch(void* const* d_in, const int* in_sizes, int n_in,
                              void* d_out, int out_size, void* d_ws, size_t ws_size,
                              hipStream_t stream) {
    const float* x         = (const float*)d_in[0];
    const float* E         = (const float*)d_in[1];
    const float* pool      = (const float*)d_in[2];
    const float* bias_pool = (const float*)d_in[3];
    const float* lin_w     = (const float*)d_in[4];
    const float* lin_b     = (const float*)d_in[5];
    const float* adj       = (const float*)d_in[6];
    float* out = (float*)d_out;

    uint8_t* ws = (uint8_t*)d_ws;
    uint16_t* A     = (uint16_t*)(ws);                 // 4096*4096*2  = 32 MiB
    uint16_t* Xtt   = (uint16_t*)(ws + 33554432);      // 2048*4096*2  = 16 MiB
    uint16_t* XG    = (uint16_t*)(ws + 50331648);      // 4096*2048*2  = 16 MiB
    uint16_t* Wt    = (uint16_t*)(ws + 67108864);      // 4096*8192*2  = 64 MiB
    float*    biasn = (float*)   (ws + 134217728);     // 4096*64*4    = 1 MiB
    float*    sd    = (float*)   (ws + 135266304);     // 16 KiB
    float*    scale = (float*)   (ws + 135282688);     // 16 KiB

    k1_dyn_adj<<<dim3(256), dim3(256), 0, stream>>>(E, A);
    k2_transpose<<<dim3(64, 32), dim3(256), 0, stream>>>(x, Xtt);
    k4a_rowsum<<<dim3(4096), dim3(256), 0, stream>>>(adj, sd, scale);
    k4b_scale<<<dim3(256), dim3(256), 0, stream>>>(adj, sd, scale);
    k5_wgen<<<dim3(1024), dim3(256), 0, stream>>>(E, pool, bias_pool, Wt, biasn);
    k3_gemm<<<dim3(16, 32), dim3(256), 0, stream>>>(A, Xtt, XG);
    k6_gconv<<<dim3(1024), dim3(256), 0, stream>>>(x, XG, Wt, biasn, scale, lin_w, lin_b, out);
}

// Round 4
// 409.721 us; speedup vs baseline: 1.4877x; 1.4877x over previous
//
#include <hip/hip_runtime.h>
#include <stdint.h>

// Problem dims
#define Bdim 32
#define Ndim 4096
#define Cin  64
#define Cout 64
#define Demb 16

typedef __bf16 bf16x8 __attribute__((ext_vector_type(8)));
typedef float  f32x4  __attribute__((ext_vector_type(4)));

#define GLOBAL_AS(p) ((__attribute__((address_space(1))) void*)(p))
#define LDS_AS(p)    ((__attribute__((address_space(3))) void*)(p))

__device__ __forceinline__ uint16_t f2bf(float x) {
    union { float f; uint32_t u; } v; v.f = x;
    uint32_t r = v.u + 0x7FFFu + ((v.u >> 16) & 1u);   // RNE, finite inputs
    return (uint16_t)(r >> 16);
}

__device__ __forceinline__ bf16x8 pack8(float4 a, float4 b) {
    union { uint16_t u[8]; bf16x8 v; } r;
    r.u[0] = f2bf(a.x); r.u[1] = f2bf(a.y); r.u[2] = f2bf(a.z); r.u[3] = f2bf(a.w);
    r.u[4] = f2bf(b.x); r.u[5] = f2bf(b.y); r.u[6] = f2bf(b.z); r.u[7] = f2bf(b.w);
    return r.v;
}

// ---------------------------------------------------------------------------
// K1: A[n][m] = softmax_m(relu(E[n]·E[m])), bf16 out.  grid 256, block 256.
// ---------------------------------------------------------------------------
__global__ __launch_bounds__(256) void k1_dyn_adj(const float* __restrict__ E,
                                                  uint16_t* __restrict__ A) {
    const int t = threadIdx.x;
    const int n0 = blockIdx.x * 16;
    __shared__ float Er_s[16][16];
    __shared__ float red_s[4];
    __shared__ float inv_s[8];

    Er_s[t >> 4][t & 15] = E[(n0 + (t >> 4)) * Demb + (t & 15)];
    __syncthreads();

    for (int half = 0; half < 2; ++half) {
        float er[8][16];
#pragma unroll
        for (int r = 0; r < 8; ++r)
#pragma unroll
            for (int d = 0; d < 16; ++d) er[r][d] = Er_s[half * 8 + r][d];

        float sacc[8];
#pragma unroll
        for (int r = 0; r < 8; ++r) sacc[r] = 0.f;

        for (int c = 0; c < 16; ++c) {
            const int m = c * 256 + t;
            const float4* ep = (const float4*)(E + (size_t)m * Demb);
            float4 e0 = ep[0], e1 = ep[1], e2 = ep[2], e3 = ep[3];
            float em[16] = {e0.x, e0.y, e0.z, e0.w, e1.x, e1.y, e1.z, e1.w,
                            e2.x, e2.y, e2.z, e2.w, e3.x, e3.y, e3.z, e3.w};
#pragma unroll
            for (int r = 0; r < 8; ++r) {
                float v = 0.f;
#pragma unroll
                for (int d = 0; d < 16; ++d) v = fmaf(er[r][d], em[d], v);
                v = fmaxf(v, 0.f);
                sacc[r] += __expf(v);
            }
        }
#pragma unroll
        for (int r = 0; r < 8; ++r) {
            float s = sacc[r];
#pragma unroll
            for (int off = 32; off > 0; off >>= 1) s += __shfl_down(s, off, 64);
            __syncthreads();
            if ((t & 63) == 0) red_s[t >> 6] = s;
            __syncthreads();
            if (t == 0) inv_s[r] = 1.f / (red_s[0] + red_s[1] + red_s[2] + red_s[3]);
        }
        __syncthreads();
        float inv[8];
#pragma unroll
        for (int r = 0; r < 8; ++r) inv[r] = inv_s[r];

        for (int c = 0; c < 16; ++c) {
            const int m = c * 256 + t;
            const float4* ep = (const float4*)(E + (size_t)m * Demb);
            float4 e0 = ep[0], e1 = ep[1], e2 = ep[2], e3 = ep[3];
            float em[16] = {e0.x, e0.y, e0.z, e0.w, e1.x, e1.y, e1.z, e1.w,
                            e2.x, e2.y, e2.z, e2.w, e3.x, e3.y, e3.z, e3.w};
#pragma unroll
            for (int r = 0; r < 8; ++r) {
                float v = 0.f;
#pragma unroll
                for (int d = 0; d < 16; ++d) v = fmaf(er[r][d], em[d], v);
                v = fmaxf(v, 0.f);
                A[(size_t)(n0 + half * 8 + r) * Ndim + m] = f2bf(__expf(v) * inv[r]);
            }
        }
        __syncthreads();
    }
}

// ---------------------------------------------------------------------------
// K2: Xtt[j = b*64+c][m] = bf16(x[b][m][c]).  grid (64 mtiles, 32 b), 256 thr.
// ---------------------------------------------------------------------------
__global__ __launch_bounds__(256) void k2_transpose(const float* __restrict__ x,
                                                    uint16_t* __restrict__ Xtt) {
    __shared__ __align__(16) uint16_t T[64][72];
    const int t = threadIdx.x;
    const int m0 = blockIdx.x * 64;
    const int b = blockIdx.y;
    const int c = t & 63;
#pragma unroll
    for (int j = 0; j < 16; ++j) {
        const int m = (t >> 6) + j * 4;
        T[c][m] = f2bf(x[((size_t)b * Ndim + (m0 + m)) * Cin + c]);
    }
    __syncthreads();
    const int c2 = t >> 2, mo = (t & 3) * 16;
    const uint4* src = (const uint4*)&T[c2][mo];
    uint4 v0 = src[0], v1 = src[1];
    uint4* dst = (uint4*)(Xtt + (size_t)(b * Cin + c2) * Ndim + m0 + mo);
    dst[0] = v0;
    dst[1] = v1;
}

// ---------------------------------------------------------------------------
// K3: XG[n][j] = sum_m A[n][m] * Xtt[j][m]   (4096 x 2048 x 4096, bf16)
// ---------------------------------------------------------------------------
#define GK 4096
#define GN 2048
__global__ __launch_bounds__(256) void k3_gemm(const uint16_t* __restrict__ Abf,
                                               const uint16_t* __restrict__ Bbf,
                                               uint16_t* __restrict__ Cbf) {
    __shared__ __align__(16) uint16_t As[128 * 32];
    __shared__ __align__(16) uint16_t Bs[128 * 32];
    const int t = threadIdx.x;
    const int lane = t & 63;
    const int w = t >> 6;
    const int wr = w >> 1, wc = w & 1;
    const int bm = blockIdx.y * 128;
    const int bn = blockIdx.x * 128;

    f32x4 acc[4][4];
#pragma unroll
    for (int i = 0; i < 4; ++i)
#pragma unroll
        for (int j = 0; j < 4; ++j) acc[i][j] = (f32x4){0.f, 0.f, 0.f, 0.f};

    const uint16_t* agp[2];
    const uint16_t* bgp[2];
    uint16_t* alp[2];
    uint16_t* blp[2];
#pragma unroll
    for (int i = 0; i < 2; ++i) {
        const int r = w * 32 + i * 16 + (lane >> 2);
        const int cg = (lane & 3) ^ ((r >> 1) & 3);
        agp[i] = Abf + (size_t)(bm + r) * GK + cg * 8;
        bgp[i] = Bbf + (size_t)(bn + r) * GK + cg * 8;
        alp[i] = &As[(w * 32 + i * 16) * 32];
        blp[i] = &Bs[(w * 32 + i * 16) * 32];
    }

    int offA[4], offB[4];
#pragma unroll
    for (int i = 0; i < 4; ++i) {
        const int m = wr * 64 + i * 16 + (lane & 15);
        offA[i] = m * 32 + (((lane >> 4) ^ ((m >> 1) & 3)) * 8);
        const int n = wc * 64 + i * 16 + (lane & 15);
        offB[i] = n * 32 + (((lane >> 4) ^ ((n >> 1) & 3)) * 8);
    }

    for (int kt = 0; kt < GK / 32; ++kt) {
#pragma unroll
        for (int i = 0; i < 2; ++i) {
            __builtin_amdgcn_global_load_lds(GLOBAL_AS(agp[i] + (size_t)kt * 32), LDS_AS(alp[i]), 16, 0, 0);
            __builtin_amdgcn_global_load_lds(GLOBAL_AS(bgp[i] + (size_t)kt * 32), LDS_AS(blp[i]), 16, 0, 0);
        }
        __syncthreads();
        bf16x8 af[4], bfr[4];
#pragma unroll
        for (int i = 0; i < 4; ++i) {
            af[i] = *(const bf16x8*)(As + offA[i]);
            bfr[i] = *(const bf16x8*)(Bs + offB[i]);
        }
#pragma unroll
        for (int i = 0; i < 4; ++i)
#pragma unroll
            for (int j = 0; j < 4; ++j)
                acc[i][j] = __builtin_amdgcn_mfma_f32_16x16x32_bf16(af[i], bfr[j], acc[i][j], 0, 0, 0);
        __syncthreads();
    }
#pragma unroll
    for (int i = 0; i < 4; ++i)
#pragma unroll
        for (int j = 0; j < 4; ++j)
#pragma unroll
            for (int r = 0; r < 4; ++r) {
                const int row = bm + wr * 64 + i * 16 + (lane >> 4) * 4 + r;
                const int col = bn + wc * 64 + j * 16 + (lane & 15);
                Cbf[(size_t)row * GN + col] = f2bf(acc[i][j][r]);
            }
}

// ---------------------------------------------------------------------------
// K4a: sd[n] = sqrt(1/(rowsum(adj[n]) + 0.5)); also zero `scale`.
// ---------------------------------------------------------------------------
__global__ __launch_bounds__(256) void k4a_rowsum(const float* __restrict__ adj,
                                                  float* __restrict__ sd,
                                                  float* __restrict__ scale) {
    const int t = threadIdx.x;
    const int n = blockIdx.x;
    const int gid = blockIdx.x * 256 + t;
    if (gid < Ndim) scale[gid] = 0.f;
    __shared__ float red_s[4];
    const float4* ap = (const float4*)(adj + (size_t)n * Ndim);
    float s = 0.f;
#pragma unroll
    for (int q = 0; q < 4; ++q) {
        float4 a = ap[q * 256 + t];
        s += a.x + a.y + a.z + a.w;
    }
#pragma unroll
    for (int off = 32; off > 0; off >>= 1) s += __shfl_down(s, off, 64);
    if ((t & 63) == 0) red_s[t >> 6] = s;
    __syncthreads();
    if (t == 0) sd[n] = sqrtf(1.f / (red_s[0] + red_s[1] + red_s[2] + red_s[3] + 0.5f));
}

__device__ __forceinline__ float block_reduce(float v, float* red_s, int t, bool domax) {
#pragma unroll
    for (int off = 32; off > 0; off >>= 1) {
        float o = __shfl_down(v, off, 64);
        v = domax ? fmaxf(v, o) : (v + o);
    }
    __syncthreads();
    if ((t & 63) == 0) red_s[t >> 6] = v;
    __syncthreads();
    return domax ? fmaxf(fmaxf(red_s[0], red_s[1]), fmaxf(red_s[2], red_s[3]))
                 : (red_s[0] + red_s[1] + red_s[2] + red_s[3]);
}

// ---------------------------------------------------------------------------
// K4b: scale[m] = sum_n softmax_row(softmax_row(sd*(adj+0.5I)*sd))[n][m]
// ---------------------------------------------------------------------------
__global__ __launch_bounds__(256) void k4b_scale(const float* __restrict__ adj,
                                                 const float* __restrict__ sd,
                                                 float* __restrict__ scale) {
    const int t = threadIdx.x;
    const int nb = blockIdx.x * 16;
    __shared__ float red_s[4];
    float sdm[16], colsum[16];
#pragma unroll
    for (int q = 0; q < 4; ++q) {
        float4 v = *(const float4*)(sd + q * 1024 + t * 4);
        sdm[q * 4 + 0] = v.x; sdm[q * 4 + 1] = v.y;
        sdm[q * 4 + 2] = v.z; sdm[q * 4 + 3] = v.w;
        colsum[q * 4 + 0] = colsum[q * 4 + 1] = colsum[q * 4 + 2] = colsum[q * 4 + 3] = 0.f;
    }
    for (int r = 0; r < 16; ++r) {
        const int n = nb + r;
        const float sdn = sd[n];
        float v[16];
#pragma unroll
        for (int q = 0; q < 4; ++q) {
            float4 a = *(const float4*)(adj + (size_t)n * Ndim + q * 1024 + t * 4);
            const int mb = q * 1024 + t * 4;
            v[q * 4 + 0] = a.x + ((mb + 0) == n ? 0.5f : 0.f);
            v[q * 4 + 1] = a.y + ((mb + 1) == n ? 0.5f : 0.f);
            v[q * 4 + 2] = a.z + ((mb + 2) == n ? 0.5f : 0.f);
            v[q * 4 + 3] = a.w + ((mb + 3) == n ? 0.5f : 0.f);
        }
        float mx = -1e30f;
#pragma unroll
        for (int i = 0; i < 16; ++i) { v[i] = sdn * v[i] * sdm[i]; mx = fmaxf(mx, v[i]); }
        mx = block_reduce(mx, red_s, t, true);
        float s1 = 0.f;
#pragma unroll
        for (int i = 0; i < 16; ++i) { v[i] = __expf(v[i] - mx); s1 += v[i]; }
        s1 = block_reduce(s1, red_s, t, false);
        const float inv1 = 1.f / s1;
        float s2 = 0.f;
#pragma unroll
        for (int i = 0; i < 16; ++i) { v[i] = __expf(v[i] * inv1); s2 += v[i]; }
        s2 = block_reduce(s2, red_s, t, false);
        const float inv2 = 1.f / s2;
#pragma unroll
        for (int i = 0; i < 16; ++i) colsum[i] += v[i] * inv2;
    }
#pragma unroll
    for (int q = 0; q < 4; ++q)
#pragma unroll
        for (int u = 0; u < 4; ++u)
            atomicAdd(scale + q * 1024 + t * 4 + u, colsum[q * 4 + u]);
}

// ---------------------------------------------------------------------------
// K5a: poolT[d][o*128 + ki] = pool[d][ki*64 + o]  (f32, 512 KB total).
// Reads coalesced; 4B scattered writes land in L2 (writeback coalesces —
// total footprint 512 KB, negligible).  grid (16 d, 4 chunks), 256 thr.
// ---------------------------------------------------------------------------
__global__ __launch_bounds__(256) void k5a_poolT(const float* __restrict__ pool,
                                                 float* __restrict__ poolT) {
    const int d = blockIdx.x;
    const int t = threadIdx.x;
    const int base = blockIdx.y * 2048;
#pragma unroll
    for (int j = 0; j < 8; ++j) {
        const int e = base + j * 256 + t;          // e = ki*64 + o
        const float v = pool[d * 8192 + e];
        poolT[d * 8192 + (e & 63) * 128 + (e >> 6)] = v;
    }
}

// ---------------------------------------------------------------------------
// K5b: Wt[n][e] = bf16(sum_d E[n,d] * poolT[d][e]), e = o*128+ki.
// Reads AND writes lane-consecutive.  Thread holds poolT[16][4] in regs
// (64 VGPRs), loops 32 nodes with En broadcast from LDS -> pool reads
// amortized 32x.  grid (8 e-chunks, 128 node-groups), 256 thr.
// Also computes biasn in ec==0 blocks.
// ---------------------------------------------------------------------------
__global__ __launch_bounds__(256) void k5b_wgen(const float* __restrict__ E,
                                                const float* __restrict__ poolT,
                                                const float* __restrict__ bias_pool,
                                                uint16_t* __restrict__ Wt,
                                                float* __restrict__ biasn) {
    const int t = threadIdx.x;
    const int ec = blockIdx.x;
    const int n0 = blockIdx.y * 32;
    __shared__ float En[32][16];
    if (t < 256) {
        En[t >> 4][t & 15] = E[(n0 + (t >> 4)) * Demb + (t & 15)];
        if (t < 256) {
            const int t2 = t + 256;
            En[t2 >> 4][t2 & 15] = E[(n0 + (t2 >> 4)) * Demb + (t2 & 15)];
        }
    }
    __syncthreads();

    const int e0 = ec * 1024 + t * 4;
    float4 P[16];
#pragma unroll
    for (int d = 0; d < 16; ++d) P[d] = *(const float4*)(poolT + d * 8192 + e0);

    for (int g = 0; g < 32; ++g) {
        float4 acc = {0.f, 0.f, 0.f, 0.f};
#pragma unroll
        for (int d = 0; d < 16; ++d) {
            const float e = En[g][d];
            acc.x = fmaf(e, P[d].x, acc.x);
            acc.y = fmaf(e, P[d].y, acc.y);
            acc.z = fmaf(e, P[d].z, acc.z);
            acc.w = fmaf(e, P[d].w, acc.w);
        }
        union { uint16_t u[4]; uint2 v; } r;
        r.u[0] = f2bf(acc.x); r.u[1] = f2bf(acc.y);
        r.u[2] = f2bf(acc.z); r.u[3] = f2bf(acc.w);
        *(uint2*)(Wt + (size_t)(n0 + g) * 8192 + e0) = r.v;
    }

    if (ec == 0) {
        const int o = t & 63, gq = t >> 6;
#pragma unroll
        for (int gi = 0; gi < 8; ++gi) {
            const int g = gi * 4 + gq;
            float a = 0.f;
#pragma unroll
            for (int d = 0; d < 16; ++d) a = fmaf(En[g][d], bias_pool[d * 64 + o], a);
            biasn[(size_t)(n0 + g) * 64 + o] = a;
        }
    }
}

// ---------------------------------------------------------------------------
// K6 (MFMA): one wave per node n.  See round-1 notes.
// ---------------------------------------------------------------------------
__global__ __launch_bounds__(256) void k6_gconv(const float* __restrict__ x,
                                                const uint16_t* __restrict__ XG,
                                                const uint16_t* __restrict__ Wt,
                                                const float* __restrict__ biasn,
                                                const float* __restrict__ scale,
                                                const float* __restrict__ lin_w,
                                                const float* __restrict__ lin_b,
                                                float* __restrict__ out) {
    __shared__ __align__(16) uint16_t Ws[4][64][136];
    __shared__ __align__(16) uint16_t Lws[64][72];
    const int t = threadIdx.x;
    const int n0 = blockIdx.x * 4;

#pragma unroll
    for (int j = 0; j < 16; ++j) {
        const int e8 = (j * 256 + t) * 8;
        const int g = e8 >> 13;
        const int r = e8 & 8191;
        uint4 v = *(const uint4*)(Wt + (size_t)(n0 + g) * 8192 + r);
        *(uint4*)&Ws[g][r >> 7][r & 127] = v;
    }
    {
        const int o = t >> 2, i0 = (t & 3) * 16;
        const float4* lp = (const float4*)(lin_w + o * 64 + i0);
        float4 a0 = lp[0], a1 = lp[1], a2 = lp[2], a3 = lp[3];
        union { uint16_t u[16]; uint4 v[2]; } r;
        r.u[0] = f2bf(a0.x); r.u[1] = f2bf(a0.y); r.u[2]  = f2bf(a0.z); r.u[3]  = f2bf(a0.w);
        r.u[4] = f2bf(a1.x); r.u[5] = f2bf(a1.y); r.u[6]  = f2bf(a1.z); r.u[7]  = f2bf(a1.w);
        r.u[8] = f2bf(a2.x); r.u[9] = f2bf(a2.y); r.u[10] = f2bf(a2.z); r.u[11] = f2bf(a2.w);
        r.u[12] = f2bf(a3.x); r.u[13] = f2bf(a3.y); r.u[14] = f2bf(a3.z); r.u[15] = f2bf(a3.w);
        *(uint4*)&Lws[o][i0] = r.v[0];
        *(uint4*)&Lws[o][i0 + 8] = r.v[1];
    }

    const int w = t >> 6, lane = t & 63;
    const int n = n0 + w;
    const int l15 = lane & 15;
    const int q8 = (lane >> 4) * 8;

    bf16x8 a[2][4];
#pragma unroll
    for (int mt = 0; mt < 2; ++mt) {
        const int b = mt * 16 + l15;
        const float* xp = x + ((size_t)b * Ndim + n) * 64 + q8;
        a[mt][0] = pack8(((const float4*)xp)[0], ((const float4*)xp)[1]);
        a[mt][1] = pack8(((const float4*)(xp + 32))[0], ((const float4*)(xp + 32))[1]);
        const uint16_t* gp = XG + (size_t)n * 2048 + b * 64 + q8;
        a[mt][2] = *(const bf16x8*)gp;
        a[mt][3] = *(const bf16x8*)(gp + 32);
    }

    f32x4 accg[2][4], accs[2][4];
#pragma unroll
    for (int mt = 0; mt < 2; ++mt)
#pragma unroll
        for (int j = 0; j < 4; ++j) {
            accg[mt][j] = (f32x4){0.f, 0.f, 0.f, 0.f};
            accs[mt][j] = (f32x4){0.f, 0.f, 0.f, 0.f};
        }

    __syncthreads();

#pragma unroll
    for (int ks = 0; ks < 4; ++ks) {
        bf16x8 bw[4];
#pragma unroll
        for (int j = 0; j < 4; ++j)
            bw[j] = *(const bf16x8*)&Ws[w][j * 16 + l15][ks * 32 + q8];
#pragma unroll
        for (int mt = 0; mt < 2; ++mt)
#pragma unroll
            for (int j = 0; j < 4; ++j)
                accg[mt][j] = __builtin_amdgcn_mfma_f32_16x16x32_bf16(a[mt][ks], bw[j], accg[mt][j], 0, 0, 0);
        if (ks < 2) {
            bf16x8 bl[4];
#pragma unroll
            for (int j = 0; j < 4; ++j)
                bl[j] = *(const bf16x8*)&Lws[j * 16 + l15][ks * 32 + q8];
#pragma unroll
            for (int mt = 0; mt < 2; ++mt)
#pragma unroll
                for (int j = 0; j < 4; ++j)
                    accs[mt][j] = __builtin_amdgcn_mfma_f32_16x16x32_bf16(a[mt][ks], bl[j], accs[mt][j], 0, 0, 0);
        }
    }

    const float sc = scale[n];
#pragma unroll
    for (int j = 0; j < 4; ++j) {
        const int o = j * 16 + l15;
        const float bn = biasn[(size_t)n * 64 + o];
        const float lb = lin_b[o];
#pragma unroll
        for (int mt = 0; mt < 2; ++mt)
#pragma unroll
            for (int r = 0; r < 4; ++r) {
                const int b = mt * 16 + (lane >> 4) * 4 + r;
                const float gg = accg[mt][j][r] + bn;
                const float xs = sc * accs[mt][j][r] + lb;
                out[((size_t)b * Ndim + n) * 64 + o] = gg + xs / (1.f + __expf(-xs));
            }
    }
}

// ---------------------------------------------------------------------------
extern "C" void kernel_launch(void* const* d_in, const int* in_sizes, int n_in,
                              void* d_out, int out_size, void* d_ws, size_t ws_size,
                              hipStream_t stream) {
    const float* x         = (const float*)d_in[0];
    const float* E         = (const float*)d_in[1];
    const float* pool      = (const float*)d_in[2];
    const float* bias_pool = (const float*)d_in[3];
    const float* lin_w     = (const float*)d_in[4];
    const float* lin_b     = (const float*)d_in[5];
    const float* adj       = (const float*)d_in[6];
    float* out = (float*)d_out;

    uint8_t* ws = (uint8_t*)d_ws;
    uint16_t* A     = (uint16_t*)(ws);                 // 4096*4096*2  = 32 MiB
    uint16_t* Xtt   = (uint16_t*)(ws + 33554432);      // 2048*4096*2  = 16 MiB
    uint16_t* XG    = (uint16_t*)(ws + 50331648);      // 4096*2048*2  = 16 MiB
    uint16_t* Wt    = (uint16_t*)(ws + 67108864);      // 4096*8192*2  = 64 MiB
    float*    biasn = (float*)   (ws + 134217728);     // 4096*64*4    = 1 MiB
    float*    sd    = (float*)   (ws + 135266304);     // 16 KiB
    float*    scale = (float*)   (ws + 135282688);     // 16 KiB
    float*    poolT = (float*)   (ws + 135299072);     // 16*8192*4    = 512 KiB

    k1_dyn_adj<<<dim3(256), dim3(256), 0, stream>>>(E, A);
    k5a_poolT<<<dim3(16, 4), dim3(256), 0, stream>>>(pool, poolT);
    k2_transpose<<<dim3(64, 32), dim3(256), 0, stream>>>(x, Xtt);
    k4a_rowsum<<<dim3(4096), dim3(256), 0, stream>>>(adj, sd, scale);
    k4b_scale<<<dim3(256), dim3(256), 0, stream>>>(adj, sd, scale);
    k5b_wgen<<<dim3(8, 128), dim3(256), 0, stream>>>(E, poolT, bias_pool, Wt, biasn);
    k3_gemm<<<dim3(16, 32), dim3(256), 0, stream>>>(A, Xtt, XG);
    k6_gconv<<<dim3(1024), dim3(256), 0, stream>>>(x, XG, Wt, biasn, scale, lin_w, lin_b, out);
}

// Round 5
// 348.782 us; speedup vs baseline: 1.7476x; 1.1747x over previous
//
#include <hip/hip_runtime.h>
#include <stdint.h>

// Problem dims
#define Bdim 32
#define Ndim 4096
#define Cin  64
#define Cout 64
#define Demb 16

typedef __bf16 bf16x8 __attribute__((ext_vector_type(8)));
typedef float  f32x4  __attribute__((ext_vector_type(4)));

#define GLOBAL_AS(p) ((__attribute__((address_space(1))) void*)(p))
#define LDS_AS(p)    ((__attribute__((address_space(3))) void*)(p))

__device__ __forceinline__ uint16_t f2bf(float x) {
    union { float f; uint32_t u; } v; v.f = x;
    uint32_t r = v.u + 0x7FFFu + ((v.u >> 16) & 1u);   // RNE, finite inputs
    return (uint16_t)(r >> 16);
}

__device__ __forceinline__ bf16x8 pack8(float4 a, float4 b) {
    union { uint16_t u[8]; bf16x8 v; } r;
    r.u[0] = f2bf(a.x); r.u[1] = f2bf(a.y); r.u[2] = f2bf(a.z); r.u[3] = f2bf(a.w);
    r.u[4] = f2bf(b.x); r.u[5] = f2bf(b.y); r.u[6] = f2bf(b.z); r.u[7] = f2bf(b.w);
    return r.v;
}

// ---------------------------------------------------------------------------
// P1: fused independent prep (blockIdx-partitioned roles, all 256-thread):
//   [0,256)      k1: A~[n][m] = bf16(exp(relu(E[n]·E[m]))) UNNORMALIZED,
//                    invA[n] = 1/rowsum  (normalization folded into k3)
//   [256,2304)   k2: Xtt[b*64+c][m] = bf16(x[b][m][c])  (LDS tile transpose)
//   [2304,6400)  k4a: sd[n] = rsqrt(rowsum(adj[n]) + 0.5); zero scale
//   [6400,6464)  k5a: poolT[d][o*128+ki] = pool[d][ki*64+o]
// ---------------------------------------------------------------------------
__global__ __launch_bounds__(256) void p1_prep(const float* __restrict__ E,
                                               const float* __restrict__ x,
                                               const float* __restrict__ adj,
                                               const float* __restrict__ pool,
                                               uint16_t* __restrict__ A,
                                               float* __restrict__ invA,
                                               uint16_t* __restrict__ Xtt,
                                               float* __restrict__ sd,
                                               float* __restrict__ scale,
                                               float* __restrict__ poolT) {
    __shared__ __align__(16) uint8_t smem[9232];
    const int t = threadIdx.x;
    const int blk = blockIdx.x;

    if (blk < 256) {
        // ---- k1: dynamic adjacency, one pass ----
        float* Er_s = (float*)smem;            // 16x16
        float* red_s = (float*)(smem + 1024);  // 4
        const int n0 = blk * 16;
        Er_s[t] = E[n0 * Demb + t];
        __syncthreads();
        for (int half = 0; half < 2; ++half) {
            float er[8][16];
#pragma unroll
            for (int r = 0; r < 8; ++r)
#pragma unroll
                for (int d = 0; d < 16; ++d) er[r][d] = Er_s[(half * 8 + r) * 16 + d];
            float sacc[8];
#pragma unroll
            for (int r = 0; r < 8; ++r) sacc[r] = 0.f;
            for (int c = 0; c < 16; ++c) {
                const int m = c * 256 + t;
                const float4* ep = (const float4*)(E + (size_t)m * Demb);
                float4 e0 = ep[0], e1 = ep[1], e2 = ep[2], e3 = ep[3];
                float em[16] = {e0.x, e0.y, e0.z, e0.w, e1.x, e1.y, e1.z, e1.w,
                                e2.x, e2.y, e2.z, e2.w, e3.x, e3.y, e3.z, e3.w};
#pragma unroll
                for (int r = 0; r < 8; ++r) {
                    float v = 0.f;
#pragma unroll
                    for (int d = 0; d < 16; ++d) v = fmaf(er[r][d], em[d], v);
                    v = fmaxf(v, 0.f);
                    const float e = __expf(v);
                    sacc[r] += e;
                    A[(size_t)(n0 + half * 8 + r) * Ndim + m] = f2bf(e);
                }
            }
#pragma unroll
            for (int r = 0; r < 8; ++r) {
                float s = sacc[r];
#pragma unroll
                for (int off = 32; off > 0; off >>= 1) s += __shfl_down(s, off, 64);
                __syncthreads();
                if ((t & 63) == 0) red_s[t >> 6] = s;
                __syncthreads();
                if (t == 0)
                    invA[n0 + half * 8 + r] = 1.f / (red_s[0] + red_s[1] + red_s[2] + red_s[3]);
            }
            __syncthreads();
        }
    } else if (blk < 2304) {
        // ---- k2: x transpose to Xtt ----
        auto T = (uint16_t(*)[72])smem;
        const int idx = blk - 256;
        const int m0 = (idx & 63) * 64;
        const int b = idx >> 6;
        const int c = t & 63;
#pragma unroll
        for (int j = 0; j < 16; ++j) {
            const int m = (t >> 6) + j * 4;
            T[c][m] = f2bf(x[((size_t)b * Ndim + (m0 + m)) * Cin + c]);
        }
        __syncthreads();
        const int c2 = t >> 2, mo = (t & 3) * 16;
        const uint4* src = (const uint4*)&T[c2][mo];
        uint4 v0 = src[0], v1 = src[1];
        uint4* dst = (uint4*)(Xtt + (size_t)(b * Cin + c2) * Ndim + m0 + mo);
        dst[0] = v0;
        dst[1] = v1;
    } else if (blk < 6400) {
        // ---- k4a: adj rowsum -> sd; zero scale ----
        float* red_s = (float*)smem;
        const int n = blk - 2304;
        if (n < 16) scale[n * 256 + t] = 0.f;
        const float4* ap = (const float4*)(adj + (size_t)n * Ndim);
        float s = 0.f;
#pragma unroll
        for (int q = 0; q < 4; ++q) {
            float4 a = ap[q * 256 + t];
            s += a.x + a.y + a.z + a.w;
        }
#pragma unroll
        for (int off = 32; off > 0; off >>= 1) s += __shfl_down(s, off, 64);
        if ((t & 63) == 0) red_s[t >> 6] = s;
        __syncthreads();
        if (t == 0) sd[n] = sqrtf(1.f / (red_s[0] + red_s[1] + red_s[2] + red_s[3] + 0.5f));
    } else {
        // ---- k5a: pool transpose ----
        const int idx = blk - 6400;
        const int d = idx >> 2;
        const int base = (idx & 3) * 2048;
#pragma unroll
        for (int j = 0; j < 8; ++j) {
            const int e = base + j * 256 + t;          // e = ki*64 + o
            const float v = pool[d * 8192 + e];
            poolT[d * 8192 + (e & 63) * 128 + (e >> 6)] = v;
        }
    }
}

__device__ __forceinline__ float block_reduce(float v, float* red_s, int t, bool domax) {
#pragma unroll
    for (int off = 32; off > 0; off >>= 1) {
        float o = __shfl_down(v, off, 64);
        v = domax ? fmaxf(v, o) : (v + o);
    }
    __syncthreads();
    if ((t & 63) == 0) red_s[t >> 6] = v;
    __syncthreads();
    return domax ? fmaxf(fmaxf(red_s[0], red_s[1]), fmaxf(red_s[2], red_s[3]))
                 : (red_s[0] + red_s[1] + red_s[2] + red_s[3]);
}

// ---------------------------------------------------------------------------
// P2: fused second phase:
//   [0,256)     k4b: scale[m] += colsum of double-softmaxed sym-normed adj
//   [256,1280)  k5b: Wt[n][o*128+ki] = bf16(sum_d E[n,d]*poolT[d][...]); biasn
// ---------------------------------------------------------------------------
__global__ __launch_bounds__(256) void p2_mid(const float* __restrict__ E,
                                              const float* __restrict__ adj,
                                              const float* __restrict__ sd,
                                              const float* __restrict__ poolT,
                                              const float* __restrict__ bias_pool,
                                              float* __restrict__ scale,
                                              uint16_t* __restrict__ Wt,
                                              float* __restrict__ biasn) {
    __shared__ __align__(16) uint8_t smem[2064];
    const int t = threadIdx.x;
    const int blk = blockIdx.x;

    if (blk < 256) {
        // ---- k4b ----
        float* red_s = (float*)smem;
        const int nb = blk * 16;
        float sdm[16], colsum[16];
#pragma unroll
        for (int q = 0; q < 4; ++q) {
            float4 v = *(const float4*)(sd + q * 1024 + t * 4);
            sdm[q * 4 + 0] = v.x; sdm[q * 4 + 1] = v.y;
            sdm[q * 4 + 2] = v.z; sdm[q * 4 + 3] = v.w;
            colsum[q * 4 + 0] = colsum[q * 4 + 1] = colsum[q * 4 + 2] = colsum[q * 4 + 3] = 0.f;
        }
        for (int r = 0; r < 16; ++r) {
            const int n = nb + r;
            const float sdn = sd[n];
            float v[16];
#pragma unroll
            for (int q = 0; q < 4; ++q) {
                float4 a = *(const float4*)(adj + (size_t)n * Ndim + q * 1024 + t * 4);
                const int mb = q * 1024 + t * 4;
                v[q * 4 + 0] = a.x + ((mb + 0) == n ? 0.5f : 0.f);
                v[q * 4 + 1] = a.y + ((mb + 1) == n ? 0.5f : 0.f);
                v[q * 4 + 2] = a.z + ((mb + 2) == n ? 0.5f : 0.f);
                v[q * 4 + 3] = a.w + ((mb + 3) == n ? 0.5f : 0.f);
            }
            float mx = -1e30f;
#pragma unroll
            for (int i = 0; i < 16; ++i) { v[i] = sdn * v[i] * sdm[i]; mx = fmaxf(mx, v[i]); }
            mx = block_reduce(mx, red_s, t, true);
            float s1 = 0.f;
#pragma unroll
            for (int i = 0; i < 16; ++i) { v[i] = __expf(v[i] - mx); s1 += v[i]; }
            s1 = block_reduce(s1, red_s, t, false);
            const float inv1 = 1.f / s1;
            float s2 = 0.f;
#pragma unroll
            for (int i = 0; i < 16; ++i) { v[i] = __expf(v[i] * inv1); s2 += v[i]; }
            s2 = block_reduce(s2, red_s, t, false);
            const float inv2 = 1.f / s2;
#pragma unroll
            for (int i = 0; i < 16; ++i) colsum[i] += v[i] * inv2;
        }
#pragma unroll
        for (int q = 0; q < 4; ++q)
#pragma unroll
            for (int u = 0; u < 4; ++u)
                atomicAdd(scale + q * 1024 + t * 4 + u, colsum[q * 4 + u]);
    } else {
        // ---- k5b ----
        float* En = (float*)smem;   // 32x16
        const int idx = blk - 256;
        const int ec = idx & 7;
        const int n0 = (idx >> 3) * 32;
        En[t] = E[n0 * Demb + t];
        En[t + 256] = E[n0 * Demb + t + 256];
        __syncthreads();

        const int e0 = ec * 1024 + t * 4;
        float4 P[16];
#pragma unroll
        for (int d = 0; d < 16; ++d) P[d] = *(const float4*)(poolT + d * 8192 + e0);

        for (int g = 0; g < 32; ++g) {
            float4 acc = {0.f, 0.f, 0.f, 0.f};
#pragma unroll
            for (int d = 0; d < 16; ++d) {
                const float e = En[g * 16 + d];
                acc.x = fmaf(e, P[d].x, acc.x);
                acc.y = fmaf(e, P[d].y, acc.y);
                acc.z = fmaf(e, P[d].z, acc.z);
                acc.w = fmaf(e, P[d].w, acc.w);
            }
            union { uint16_t u[4]; uint2 v; } r;
            r.u[0] = f2bf(acc.x); r.u[1] = f2bf(acc.y);
            r.u[2] = f2bf(acc.z); r.u[3] = f2bf(acc.w);
            *(uint2*)(Wt + (size_t)(n0 + g) * 8192 + e0) = r.v;
        }

        if (ec == 0) {
            const int o = t & 63, gq = t >> 6;
#pragma unroll
            for (int gi = 0; gi < 8; ++gi) {
                const int g = gi * 4 + gq;
                float a = 0.f;
#pragma unroll
                for (int d = 0; d < 16; ++d) a = fmaf(En[g * 16 + d], bias_pool[d * 64 + o], a);
                biasn[(size_t)(n0 + g) * 64 + o] = a;
            }
        }
    }
}

// ---------------------------------------------------------------------------
// K3: XG[n][j] = invA[n] * sum_m A~[n][m] * Xtt[j][m]  (4096 x 2048 x 4096)
// m97-style 128x128 tile, BK=32, global_load_lds w=16, XOR chunk swizzle.
// Row normalization (invA) folded into the epilogue.
// ---------------------------------------------------------------------------
#define GK 4096
#define GN 2048
__global__ __launch_bounds__(256) void k3_gemm(const uint16_t* __restrict__ Abf,
                                               const uint16_t* __restrict__ Bbf,
                                               const float* __restrict__ invA,
                                               uint16_t* __restrict__ Cbf) {
    __shared__ __align__(16) uint16_t As[128 * 32];
    __shared__ __align__(16) uint16_t Bs[128 * 32];
    const int t = threadIdx.x;
    const int lane = t & 63;
    const int w = t >> 6;
    const int wr = w >> 1, wc = w & 1;
    const int bm = blockIdx.y * 128;
    const int bn = blockIdx.x * 128;

    f32x4 acc[4][4];
#pragma unroll
    for (int i = 0; i < 4; ++i)
#pragma unroll
        for (int j = 0; j < 4; ++j) acc[i][j] = (f32x4){0.f, 0.f, 0.f, 0.f};

    const uint16_t* agp[2];
    const uint16_t* bgp[2];
    uint16_t* alp[2];
    uint16_t* blp[2];
#pragma unroll
    for (int i = 0; i < 2; ++i) {
        const int r = w * 32 + i * 16 + (lane >> 2);
        const int cg = (lane & 3) ^ ((r >> 1) & 3);
        agp[i] = Abf + (size_t)(bm + r) * GK + cg * 8;
        bgp[i] = Bbf + (size_t)(bn + r) * GK + cg * 8;
        alp[i] = &As[(w * 32 + i * 16) * 32];
        blp[i] = &Bs[(w * 32 + i * 16) * 32];
    }

    int offA[4], offB[4];
#pragma unroll
    for (int i = 0; i < 4; ++i) {
        const int m = wr * 64 + i * 16 + (lane & 15);
        offA[i] = m * 32 + (((lane >> 4) ^ ((m >> 1) & 3)) * 8);
        const int n = wc * 64 + i * 16 + (lane & 15);
        offB[i] = n * 32 + (((lane >> 4) ^ ((n >> 1) & 3)) * 8);
    }

    for (int kt = 0; kt < GK / 32; ++kt) {
#pragma unroll
        for (int i = 0; i < 2; ++i) {
            __builtin_amdgcn_global_load_lds(GLOBAL_AS(agp[i] + (size_t)kt * 32), LDS_AS(alp[i]), 16, 0, 0);
            __builtin_amdgcn_global_load_lds(GLOBAL_AS(bgp[i] + (size_t)kt * 32), LDS_AS(blp[i]), 16, 0, 0);
        }
        __syncthreads();
        bf16x8 af[4], bfr[4];
#pragma unroll
        for (int i = 0; i < 4; ++i) {
            af[i] = *(const bf16x8*)(As + offA[i]);
            bfr[i] = *(const bf16x8*)(Bs + offB[i]);
        }
#pragma unroll
        for (int i = 0; i < 4; ++i)
#pragma unroll
            for (int j = 0; j < 4; ++j)
                acc[i][j] = __builtin_amdgcn_mfma_f32_16x16x32_bf16(af[i], bfr[j], acc[i][j], 0, 0, 0);
        __syncthreads();
    }
#pragma unroll
    for (int i = 0; i < 4; ++i) {
        float invv[4];
#pragma unroll
        for (int r = 0; r < 4; ++r)
            invv[r] = invA[bm + wr * 64 + i * 16 + (lane >> 4) * 4 + r];
#pragma unroll
        for (int j = 0; j < 4; ++j)
#pragma unroll
            for (int r = 0; r < 4; ++r) {
                const int row = bm + wr * 64 + i * 16 + (lane >> 4) * 4 + r;
                const int col = bn + wc * 64 + j * 16 + (lane & 15);
                Cbf[(size_t)row * GN + col] = f2bf(acc[i][j][r] * invv[r]);
            }
    }
}

// ---------------------------------------------------------------------------
// K6 (MFMA): one wave per node n.  Unchanged from round 2.
// ---------------------------------------------------------------------------
__global__ __launch_bounds__(256) void k6_gconv(const float* __restrict__ x,
                                                const uint16_t* __restrict__ XG,
                                                const uint16_t* __restrict__ Wt,
                                                const float* __restrict__ biasn,
                                                const float* __restrict__ scale,
                                                const float* __restrict__ lin_w,
                                                const float* __restrict__ lin_b,
                                                float* __restrict__ out) {
    __shared__ __align__(16) uint16_t Ws[4][64][136];
    __shared__ __align__(16) uint16_t Lws[64][72];
    const int t = threadIdx.x;
    const int n0 = blockIdx.x * 4;

#pragma unroll
    for (int j = 0; j < 16; ++j) {
        const int e8 = (j * 256 + t) * 8;
        const int g = e8 >> 13;
        const int r = e8 & 8191;
        uint4 v = *(const uint4*)(Wt + (size_t)(n0 + g) * 8192 + r);
        *(uint4*)&Ws[g][r >> 7][r & 127] = v;
    }
    {
        const int o = t >> 2, i0 = (t & 3) * 16;
        const float4* lp = (const float4*)(lin_w + o * 64 + i0);
        float4 a0 = lp[0], a1 = lp[1], a2 = lp[2], a3 = lp[3];
        union { uint16_t u[16]; uint4 v[2]; } r;
        r.u[0] = f2bf(a0.x); r.u[1] = f2bf(a0.y); r.u[2]  = f2bf(a0.z); r.u[3]  = f2bf(a0.w);
        r.u[4] = f2bf(a1.x); r.u[5] = f2bf(a1.y); r.u[6]  = f2bf(a1.z); r.u[7]  = f2bf(a1.w);
        r.u[8] = f2bf(a2.x); r.u[9] = f2bf(a2.y); r.u[10] = f2bf(a2.z); r.u[11] = f2bf(a2.w);
        r.u[12] = f2bf(a3.x); r.u[13] = f2bf(a3.y); r.u[14] = f2bf(a3.z); r.u[15] = f2bf(a3.w);
        *(uint4*)&Lws[o][i0] = r.v[0];
        *(uint4*)&Lws[o][i0 + 8] = r.v[1];
    }

    const int w = t >> 6, lane = t & 63;
    const int n = n0 + w;
    const int l15 = lane & 15;
    const int q8 = (lane >> 4) * 8;

    bf16x8 a[2][4];
#pragma unroll
    for (int mt = 0; mt < 2; ++mt) {
        const int b = mt * 16 + l15;
        const float* xp = x + ((size_t)b * Ndim + n) * 64 + q8;
        a[mt][0] = pack8(((const float4*)xp)[0], ((const float4*)xp)[1]);
        a[mt][1] = pack8(((const float4*)(xp + 32))[0], ((const float4*)(xp + 32))[1]);
        const uint16_t* gp = XG + (size_t)n * 2048 + b * 64 + q8;
        a[mt][2] = *(const bf16x8*)gp;
        a[mt][3] = *(const bf16x8*)(gp + 32);
    }

    f32x4 accg[2][4], accs[2][4];
#pragma unroll
    for (int mt = 0; mt < 2; ++mt)
#pragma unroll
        for (int j = 0; j < 4; ++j) {
            accg[mt][j] = (f32x4){0.f, 0.f, 0.f, 0.f};
            accs[mt][j] = (f32x4){0.f, 0.f, 0.f, 0.f};
        }

    __syncthreads();

#pragma unroll
    for (int ks = 0; ks < 4; ++ks) {
        bf16x8 bw[4];
#pragma unroll
        for (int j = 0; j < 4; ++j)
            bw[j] = *(const bf16x8*)&Ws[w][j * 16 + l15][ks * 32 + q8];
#pragma unroll
        for (int mt = 0; mt < 2; ++mt)
#pragma unroll
            for (int j = 0; j < 4; ++j)
                accg[mt][j] = __builtin_amdgcn_mfma_f32_16x16x32_bf16(a[mt][ks], bw[j], accg[mt][j], 0, 0, 0);
        if (ks < 2) {
            bf16x8 bl[4];
#pragma unroll
            for (int j = 0; j < 4; ++j)
                bl[j] = *(const bf16x8*)&Lws[j * 16 + l15][ks * 32 + q8];
#pragma unroll
            for (int mt = 0; mt < 2; ++mt)
#pragma unroll
                for (int j = 0; j < 4; ++j)
                    accs[mt][j] = __builtin_amdgcn_mfma_f32_16x16x32_bf16(a[mt][ks], bl[j], accs[mt][j], 0, 0, 0);
        }
    }

    const float sc = scale[n];
#pragma unroll
    for (int j = 0; j < 4; ++j) {
        const int o = j * 16 + l15;
        const float bn = biasn[(size_t)n * 64 + o];
        const float lb = lin_b[o];
#pragma unroll
        for (int mt = 0; mt < 2; ++mt)
#pragma unroll
            for (int r = 0; r < 4; ++r) {
                const int b = mt * 16 + (lane >> 4) * 4 + r;
                const float gg = accg[mt][j][r] + bn;
                const float xs = sc * accs[mt][j][r] + lb;
                out[((size_t)b * Ndim + n) * 64 + o] = gg + xs / (1.f + __expf(-xs));
            }
    }
}

// ---------------------------------------------------------------------------
extern "C" void kernel_launch(void* const* d_in, const int* in_sizes, int n_in,
                              void* d_out, int out_size, void* d_ws, size_t ws_size,
                              hipStream_t stream) {
    const float* x         = (const float*)d_in[0];
    const float* E         = (const float*)d_in[1];
    const float* pool      = (const float*)d_in[2];
    const float* bias_pool = (const float*)d_in[3];
    const float* lin_w     = (const float*)d_in[4];
    const float* lin_b     = (const float*)d_in[5];
    const float* adj       = (const float*)d_in[6];
    float* out = (float*)d_out;

    uint8_t* ws = (uint8_t*)d_ws;
    uint16_t* A     = (uint16_t*)(ws);                 // 4096*4096*2  = 32 MiB
    uint16_t* Xtt   = (uint16_t*)(ws + 33554432);      // 2048*4096*2  = 16 MiB
    uint16_t* XG    = (uint16_t*)(ws + 50331648);      // 4096*2048*2  = 16 MiB
    uint16_t* Wt    = (uint16_t*)(ws + 67108864);      // 4096*8192*2  = 64 MiB
    float*    biasn = (float*)   (ws + 134217728);     // 4096*64*4    = 1 MiB
    float*    sd    = (float*)   (ws + 135266304);     // 16 KiB
    float*    scale = (float*)   (ws + 135282688);     // 16 KiB
    float*    poolT = (float*)   (ws + 135299072);     // 512 KiB
    float*    invA  = (float*)   (ws + 135823360);     // 16 KiB

    p1_prep<<<dim3(6464), dim3(256), 0, stream>>>(E, x, adj, pool, A, invA, Xtt, sd, scale, poolT);
    p2_mid<<<dim3(1280), dim3(256), 0, stream>>>(E, adj, sd, poolT, bias_pool, scale, Wt, biasn);
    k3_gemm<<<dim3(16, 32), dim3(256), 0, stream>>>(A, Xtt, invA, XG);
    k6_gconv<<<dim3(1024), dim3(256), 0, stream>>>(x, XG, Wt, biasn, scale, lin_w, lin_b, out);
}

// Round 6
// 338.673 us; speedup vs baseline: 1.7997x; 1.0298x over previous
//
#include <hip/hip_runtime.h>
#include <stdint.h>

// Problem dims
#define Bdim 32
#define Ndim 4096
#define Cin  64
#define Cout 64
#define Demb 16

typedef __bf16 bf16x8 __attribute__((ext_vector_type(8)));
typedef float  f32x4  __attribute__((ext_vector_type(4)));

#define GLOBAL_AS(p) ((__attribute__((address_space(1))) void*)(p))
#define LDS_AS(p)    ((__attribute__((address_space(3))) void*)(p))

__device__ __forceinline__ uint16_t f2bf(float x) {
    union { float f; uint32_t u; } v; v.f = x;
    uint32_t r = v.u + 0x7FFFu + ((v.u >> 16) & 1u);   // RNE, finite inputs
    return (uint16_t)(r >> 16);
}

__device__ __forceinline__ bf16x8 pack8(float4 a, float4 b) {
    union { uint16_t u[8]; bf16x8 v; } r;
    r.u[0] = f2bf(a.x); r.u[1] = f2bf(a.y); r.u[2] = f2bf(a.z); r.u[3] = f2bf(a.w);
    r.u[4] = f2bf(b.x); r.u[5] = f2bf(b.y); r.u[6] = f2bf(b.z); r.u[7] = f2bf(b.w);
    return r.v;
}

// ---------------------------------------------------------------------------
// P1: fused independent prep (blockIdx-partitioned roles, all 256-thread):
//   [0,256)      k1: A~[n][m] = bf16(exp(relu(E[n]·E[m]))) UNNORMALIZED,
//                    invA[n] = 1/rowsum  (normalization folded into k3)
//   [256,2304)   k2: Xtt[b*64+c][m] = bf16(x[b][m][c])  (LDS tile transpose)
//   [2304,6400)  k4a: sd[n] = rsqrt(rowsum(adj[n]) + 0.5); zero scale
//   [6400,6464)  k5a: poolT[d][o*128+ki] = pool[d][ki*64+o]
// ---------------------------------------------------------------------------
__global__ __launch_bounds__(256) void p1_prep(const float* __restrict__ E,
                                               const float* __restrict__ x,
                                               const float* __restrict__ adj,
                                               const float* __restrict__ pool,
                                               uint16_t* __restrict__ A,
                                               float* __restrict__ invA,
                                               uint16_t* __restrict__ Xtt,
                                               float* __restrict__ sd,
                                               float* __restrict__ scale,
                                               float* __restrict__ poolT) {
    __shared__ __align__(16) uint8_t smem[9232];
    const int t = threadIdx.x;
    const int blk = blockIdx.x;

    if (blk < 256) {
        // ---- k1: dynamic adjacency, one pass ----
        float* Er_s = (float*)smem;            // 16x16
        float* red_s = (float*)(smem + 1024);  // 4
        const int n0 = blk * 16;
        Er_s[t] = E[n0 * Demb + t];
        __syncthreads();
        for (int half = 0; half < 2; ++half) {
            float er[8][16];
#pragma unroll
            for (int r = 0; r < 8; ++r)
#pragma unroll
                for (int d = 0; d < 16; ++d) er[r][d] = Er_s[(half * 8 + r) * 16 + d];
            float sacc[8];
#pragma unroll
            for (int r = 0; r < 8; ++r) sacc[r] = 0.f;
            for (int c = 0; c < 16; ++c) {
                const int m = c * 256 + t;
                const float4* ep = (const float4*)(E + (size_t)m * Demb);
                float4 e0 = ep[0], e1 = ep[1], e2 = ep[2], e3 = ep[3];
                float em[16] = {e0.x, e0.y, e0.z, e0.w, e1.x, e1.y, e1.z, e1.w,
                                e2.x, e2.y, e2.z, e2.w, e3.x, e3.y, e3.z, e3.w};
#pragma unroll
                for (int r = 0; r < 8; ++r) {
                    float v = 0.f;
#pragma unroll
                    for (int d = 0; d < 16; ++d) v = fmaf(er[r][d], em[d], v);
                    v = fmaxf(v, 0.f);
                    const float e = __expf(v);
                    sacc[r] += e;
                    A[(size_t)(n0 + half * 8 + r) * Ndim + m] = f2bf(e);
                }
            }
#pragma unroll
            for (int r = 0; r < 8; ++r) {
                float s = sacc[r];
#pragma unroll
                for (int off = 32; off > 0; off >>= 1) s += __shfl_down(s, off, 64);
                __syncthreads();
                if ((t & 63) == 0) red_s[t >> 6] = s;
                __syncthreads();
                if (t == 0)
                    invA[n0 + half * 8 + r] = 1.f / (red_s[0] + red_s[1] + red_s[2] + red_s[3]);
            }
            __syncthreads();
        }
    } else if (blk < 2304) {
        // ---- k2: x transpose to Xtt ----
        auto T = (uint16_t(*)[72])smem;
        const int idx = blk - 256;
        const int m0 = (idx & 63) * 64;
        const int b = idx >> 6;
        const int c = t & 63;
#pragma unroll
        for (int j = 0; j < 16; ++j) {
            const int m = (t >> 6) + j * 4;
            T[c][m] = f2bf(x[((size_t)b * Ndim + (m0 + m)) * Cin + c]);
        }
        __syncthreads();
        const int c2 = t >> 2, mo = (t & 3) * 16;
        const uint4* src = (const uint4*)&T[c2][mo];
        uint4 v0 = src[0], v1 = src[1];
        uint4* dst = (uint4*)(Xtt + (size_t)(b * Cin + c2) * Ndim + m0 + mo);
        dst[0] = v0;
        dst[1] = v1;
    } else if (blk < 6400) {
        // ---- k4a: adj rowsum -> sd; zero scale ----
        float* red_s = (float*)smem;
        const int n = blk - 2304;
        if (n < 16) scale[n * 256 + t] = 0.f;
        const float4* ap = (const float4*)(adj + (size_t)n * Ndim);
        float s = 0.f;
#pragma unroll
        for (int q = 0; q < 4; ++q) {
            float4 a = ap[q * 256 + t];
            s += a.x + a.y + a.z + a.w;
        }
#pragma unroll
        for (int off = 32; off > 0; off >>= 1) s += __shfl_down(s, off, 64);
        if ((t & 63) == 0) red_s[t >> 6] = s;
        __syncthreads();
        if (t == 0) sd[n] = sqrtf(1.f / (red_s[0] + red_s[1] + red_s[2] + red_s[3] + 0.5f));
    } else {
        // ---- k5a: pool transpose ----
        const int idx = blk - 6400;
        const int d = idx >> 2;
        const int base = (idx & 3) * 2048;
#pragma unroll
        for (int j = 0; j < 8; ++j) {
            const int e = base + j * 256 + t;          // e = ki*64 + o
            const float v = pool[d * 8192 + e];
            poolT[d * 8192 + (e & 63) * 128 + (e >> 6)] = v;
        }
    }
}

__device__ __forceinline__ float block_reduce_sum(float v, float* red_s, int t) {
#pragma unroll
    for (int off = 32; off > 0; off >>= 1) v += __shfl_down(v, off, 64);
    __syncthreads();
    if ((t & 63) == 0) red_s[t >> 6] = v;
    __syncthreads();
    return red_s[0] + red_s[1] + red_s[2] + red_s[3];
}

// ---------------------------------------------------------------------------
// P2 (mega): k3 MFMA GEMM + k4b scale + k5b Wt-gen co-resident in one launch.
//   [0,512)     k3: XG[n][j] = invA[n]*sum_m A~[n][m]*Xtt[j][m]
//               (128x128 tile, BK=32, global_load_lds w=16, XOR swizzle)
//   [512,768)   k4b: scale[m] += colsum(rowsoftmax(rowsoftmax(sym-norm adj)))
//               (max pass dropped: exp args bounded by ~4, shift-invariant)
//   [768,1792)  k5b: Wt[n][o*128+ki] = bf16(sum_d E[n,d]*poolT[d][...]); biasn
// k4b/k5b latency+store work hides under k3's MFMA instead of serializing.
// ---------------------------------------------------------------------------
#define GK 4096
#define GN 2048
__global__ __launch_bounds__(256) void p2_fused(const uint16_t* __restrict__ Abf,
                                                const uint16_t* __restrict__ Bbf,
                                                const float* __restrict__ invA,
                                                uint16_t* __restrict__ Cbf,
                                                const float* __restrict__ E,
                                                const float* __restrict__ adj,
                                                const float* __restrict__ sd,
                                                const float* __restrict__ poolT,
                                                const float* __restrict__ bias_pool,
                                                float* __restrict__ scale,
                                                uint16_t* __restrict__ Wt,
                                                float* __restrict__ biasn) {
    __shared__ __align__(16) uint8_t smem[16384];
    const int t = threadIdx.x;
    const int blk = blockIdx.x;

    if (blk < 512) {
        // ---- k3: MFMA GEMM ----
        uint16_t* As = (uint16_t*)smem;
        uint16_t* Bs = (uint16_t*)(smem + 8192);
        const int lane = t & 63;
        const int w = t >> 6;
        const int wr = w >> 1, wc = w & 1;
        const int bm = (blk >> 4) * 128;
        const int bn = (blk & 15) * 128;

        f32x4 acc[4][4];
#pragma unroll
        for (int i = 0; i < 4; ++i)
#pragma unroll
            for (int j = 0; j < 4; ++j) acc[i][j] = (f32x4){0.f, 0.f, 0.f, 0.f};

        const uint16_t* agp[2];
        const uint16_t* bgp[2];
        uint16_t* alp[2];
        uint16_t* blp[2];
#pragma unroll
        for (int i = 0; i < 2; ++i) {
            const int r = w * 32 + i * 16 + (lane >> 2);
            const int cg = (lane & 3) ^ ((r >> 1) & 3);
            agp[i] = Abf + (size_t)(bm + r) * GK + cg * 8;
            bgp[i] = Bbf + (size_t)(bn + r) * GK + cg * 8;
            alp[i] = &As[(w * 32 + i * 16) * 32];
            blp[i] = &Bs[(w * 32 + i * 16) * 32];
        }

        int offA[4], offB[4];
#pragma unroll
        for (int i = 0; i < 4; ++i) {
            const int m = wr * 64 + i * 16 + (lane & 15);
            offA[i] = m * 32 + (((lane >> 4) ^ ((m >> 1) & 3)) * 8);
            const int n = wc * 64 + i * 16 + (lane & 15);
            offB[i] = n * 32 + (((lane >> 4) ^ ((n >> 1) & 3)) * 8);
        }

        for (int kt = 0; kt < GK / 32; ++kt) {
#pragma unroll
            for (int i = 0; i < 2; ++i) {
                __builtin_amdgcn_global_load_lds(GLOBAL_AS(agp[i] + (size_t)kt * 32), LDS_AS(alp[i]), 16, 0, 0);
                __builtin_amdgcn_global_load_lds(GLOBAL_AS(bgp[i] + (size_t)kt * 32), LDS_AS(blp[i]), 16, 0, 0);
            }
            __syncthreads();
            bf16x8 af[4], bfr[4];
#pragma unroll
            for (int i = 0; i < 4; ++i) {
                af[i] = *(const bf16x8*)(As + offA[i]);
                bfr[i] = *(const bf16x8*)(Bs + offB[i]);
            }
#pragma unroll
            for (int i = 0; i < 4; ++i)
#pragma unroll
                for (int j = 0; j < 4; ++j)
                    acc[i][j] = __builtin_amdgcn_mfma_f32_16x16x32_bf16(af[i], bfr[j], acc[i][j], 0, 0, 0);
            __syncthreads();
        }
#pragma unroll
        for (int i = 0; i < 4; ++i) {
            float invv[4];
#pragma unroll
            for (int r = 0; r < 4; ++r)
                invv[r] = invA[bm + wr * 64 + i * 16 + (lane >> 4) * 4 + r];
#pragma unroll
            for (int j = 0; j < 4; ++j)
#pragma unroll
                for (int r = 0; r < 4; ++r) {
                    const int row = bm + wr * 64 + i * 16 + (lane >> 4) * 4 + r;
                    const int col = bn + wc * 64 + j * 16 + (lane & 15);
                    Cbf[(size_t)row * GN + col] = f2bf(acc[i][j][r] * invv[r]);
                }
        }
    } else if (blk < 768) {
        // ---- k4b (no max pass: args bounded, softmax shift-invariant) ----
        float* red_s = (float*)smem;
        const int nb = (blk - 512) * 16;
        float sdm[16], colsum[16];
#pragma unroll
        for (int q = 0; q < 4; ++q) {
            float4 v = *(const float4*)(sd + q * 1024 + t * 4);
            sdm[q * 4 + 0] = v.x; sdm[q * 4 + 1] = v.y;
            sdm[q * 4 + 2] = v.z; sdm[q * 4 + 3] = v.w;
            colsum[q * 4 + 0] = colsum[q * 4 + 1] = colsum[q * 4 + 2] = colsum[q * 4 + 3] = 0.f;
        }
        for (int r = 0; r < 16; ++r) {
            const int n = nb + r;
            const float sdn = sd[n];
            float v[16];
#pragma unroll
            for (int q = 0; q < 4; ++q) {
                float4 a = *(const float4*)(adj + (size_t)n * Ndim + q * 1024 + t * 4);
                const int mb = q * 1024 + t * 4;
                v[q * 4 + 0] = a.x + ((mb + 0) == n ? 0.5f : 0.f);
                v[q * 4 + 1] = a.y + ((mb + 1) == n ? 0.5f : 0.f);
                v[q * 4 + 2] = a.z + ((mb + 2) == n ? 0.5f : 0.f);
                v[q * 4 + 3] = a.w + ((mb + 3) == n ? 0.5f : 0.f);
            }
            float s1 = 0.f;
#pragma unroll
            for (int i = 0; i < 16; ++i) { v[i] = __expf(sdn * v[i] * sdm[i]); s1 += v[i]; }
            s1 = block_reduce_sum(s1, red_s, t);
            const float inv1 = 1.f / s1;
            float s2 = 0.f;
#pragma unroll
            for (int i = 0; i < 16; ++i) { v[i] = __expf(v[i] * inv1); s2 += v[i]; }
            s2 = block_reduce_sum(s2, red_s, t);
            const float inv2 = 1.f / s2;
#pragma unroll
            for (int i = 0; i < 16; ++i) colsum[i] += v[i] * inv2;
        }
#pragma unroll
        for (int q = 0; q < 4; ++q)
#pragma unroll
            for (int u = 0; u < 4; ++u)
                atomicAdd(scale + q * 1024 + t * 4 + u, colsum[q * 4 + u]);
    } else {
        // ---- k5b ----
        float* En = (float*)smem;   // 32x16
        const int idx = blk - 768;
        const int ec = idx & 7;
        const int n0 = (idx >> 3) * 32;
        En[t] = E[n0 * Demb + t];
        En[t + 256] = E[n0 * Demb + t + 256];
        __syncthreads();

        const int e0 = ec * 1024 + t * 4;
        float4 P[16];
#pragma unroll
        for (int d = 0; d < 16; ++d) P[d] = *(const float4*)(poolT + d * 8192 + e0);

        for (int g = 0; g < 32; ++g) {
            float4 acc = {0.f, 0.f, 0.f, 0.f};
#pragma unroll
            for (int d = 0; d < 16; ++d) {
                const float e = En[g * 16 + d];
                acc.x = fmaf(e, P[d].x, acc.x);
                acc.y = fmaf(e, P[d].y, acc.y);
                acc.z = fmaf(e, P[d].z, acc.z);
                acc.w = fmaf(e, P[d].w, acc.w);
            }
            union { uint16_t u[4]; uint2 v; } r;
            r.u[0] = f2bf(acc.x); r.u[1] = f2bf(acc.y);
            r.u[2] = f2bf(acc.z); r.u[3] = f2bf(acc.w);
            *(uint2*)(Wt + (size_t)(n0 + g) * 8192 + e0) = r.v;
        }

        if (ec == 0) {
            const int o = t & 63, gq = t >> 6;
#pragma unroll
            for (int gi = 0; gi < 8; ++gi) {
                const int g = gi * 4 + gq;
                float a = 0.f;
#pragma unroll
                for (int d = 0; d < 16; ++d) a = fmaf(En[g * 16 + d], bias_pool[d * 64 + o], a);
                biasn[(size_t)(n0 + g) * 64 + o] = a;
            }
        }
    }
}

// ---------------------------------------------------------------------------
// K6 (MFMA, no W staging): one wave per node n.  B-fragments of Wt load
// DIRECTLY from global (each element consumed exactly once — LDS staging
// bought zero reuse; addresses form 16 fully-used 64B sectors per load).
// LDS = lin_w image only (9 KB) -> occupancy up, one barrier fewer.
// ---------------------------------------------------------------------------
__global__ __launch_bounds__(256) void k6_gconv(const float* __restrict__ x,
                                                const uint16_t* __restrict__ XG,
                                                const uint16_t* __restrict__ Wt,
                                                const float* __restrict__ biasn,
                                                const float* __restrict__ scale,
                                                const float* __restrict__ lin_w,
                                                const float* __restrict__ lin_b,
                                                float* __restrict__ out) {
    __shared__ __align__(16) uint16_t Lws[64][72];
    const int t = threadIdx.x;
    const int n0 = blockIdx.x * 4;

    {
        const int o = t >> 2, i0 = (t & 3) * 16;
        const float4* lp = (const float4*)(lin_w + o * 64 + i0);
        float4 a0 = lp[0], a1 = lp[1], a2 = lp[2], a3 = lp[3];
        union { uint16_t u[16]; uint4 v[2]; } r;
        r.u[0] = f2bf(a0.x); r.u[1] = f2bf(a0.y); r.u[2]  = f2bf(a0.z); r.u[3]  = f2bf(a0.w);
        r.u[4] = f2bf(a1.x); r.u[5] = f2bf(a1.y); r.u[6]  = f2bf(a1.z); r.u[7]  = f2bf(a1.w);
        r.u[8] = f2bf(a2.x); r.u[9] = f2bf(a2.y); r.u[10] = f2bf(a2.z); r.u[11] = f2bf(a2.w);
        r.u[12] = f2bf(a3.x); r.u[13] = f2bf(a3.y); r.u[14] = f2bf(a3.z); r.u[15] = f2bf(a3.w);
        *(uint4*)&Lws[o][i0] = r.v[0];
        *(uint4*)&Lws[o][i0 + 8] = r.v[1];
    }

    const int w = t >> 6, lane = t & 63;
    const int n = n0 + w;
    const int l15 = lane & 15;
    const int q8 = (lane >> 4) * 8;

    bf16x8 a[2][4];
#pragma unroll
    for (int mt = 0; mt < 2; ++mt) {
        const int b = mt * 16 + l15;
        const float* xp = x + ((size_t)b * Ndim + n) * 64 + q8;
        a[mt][0] = pack8(((const float4*)xp)[0], ((const float4*)xp)[1]);
        a[mt][1] = pack8(((const float4*)(xp + 32))[0], ((const float4*)(xp + 32))[1]);
        const uint16_t* gp = XG + (size_t)n * 2048 + b * 64 + q8;
        a[mt][2] = *(const bf16x8*)gp;
        a[mt][3] = *(const bf16x8*)(gp + 32);
    }

    f32x4 accg[2][4], accs[2][4];
#pragma unroll
    for (int mt = 0; mt < 2; ++mt)
#pragma unroll
        for (int j = 0; j < 4; ++j) {
            accg[mt][j] = (f32x4){0.f, 0.f, 0.f, 0.f};
            accs[mt][j] = (f32x4){0.f, 0.f, 0.f, 0.f};
        }

    const uint16_t* wp = Wt + (size_t)n * 8192 + l15 * 128 + q8;

    __syncthreads();   // Lws ready

#pragma unroll
    for (int ks = 0; ks < 4; ++ks) {
        bf16x8 bw[4];
#pragma unroll
        for (int j = 0; j < 4; ++j)
            bw[j] = *(const bf16x8*)(wp + j * 2048 + ks * 32);
#pragma unroll
        for (int mt = 0; mt < 2; ++mt)
#pragma unroll
            for (int j = 0; j < 4; ++j)
                accg[mt][j] = __builtin_amdgcn_mfma_f32_16x16x32_bf16(a[mt][ks], bw[j], accg[mt][j], 0, 0, 0);
        if (ks < 2) {
            bf16x8 bl[4];
#pragma unroll
            for (int j = 0; j < 4; ++j)
                bl[j] = *(const bf16x8*)&Lws[j * 16 + l15][ks * 32 + q8];
#pragma unroll
            for (int mt = 0; mt < 2; ++mt)
#pragma unroll
                for (int j = 0; j < 4; ++j)
                    accs[mt][j] = __builtin_amdgcn_mfma_f32_16x16x32_bf16(a[mt][ks], bl[j], accs[mt][j], 0, 0, 0);
        }
    }

    const float sc = scale[n];
#pragma unroll
    for (int j = 0; j < 4; ++j) {
        const int o = j * 16 + l15;
        const float bn = biasn[(size_t)n * 64 + o];
        const float lb = lin_b[o];
#pragma unroll
        for (int mt = 0; mt < 2; ++mt)
#pragma unroll
            for (int r = 0; r < 4; ++r) {
                const int b = mt * 16 + (lane >> 4) * 4 + r;
                const float gg = accg[mt][j][r] + bn;
                const float xs = sc * accs[mt][j][r] + lb;
                out[((size_t)b * Ndim + n) * 64 + o] = gg + xs / (1.f + __expf(-xs));
            }
    }
}

// ---------------------------------------------------------------------------
extern "C" void kernel_launch(void* const* d_in, const int* in_sizes, int n_in,
                              void* d_out, int out_size, void* d_ws, size_t ws_size,
                              hipStream_t stream) {
    const float* x         = (const float*)d_in[0];
    const float* E         = (const float*)d_in[1];
    const float* pool      = (const float*)d_in[2];
    const float* bias_pool = (const float*)d_in[3];
    const float* lin_w     = (const float*)d_in[4];
    const float* lin_b     = (const float*)d_in[5];
    const float* adj       = (const float*)d_in[6];
    float* out = (float*)d_out;

    uint8_t* ws = (uint8_t*)d_ws;
    uint16_t* A     = (uint16_t*)(ws);                 // 4096*4096*2  = 32 MiB
    uint16_t* Xtt   = (uint16_t*)(ws + 33554432);      // 2048*4096*2  = 16 MiB
    uint16_t* XG    = (uint16_t*)(ws + 50331648);      // 4096*2048*2  = 16 MiB
    uint16_t* Wt    = (uint16_t*)(ws + 67108864);      // 4096*8192*2  = 64 MiB
    float*    biasn = (float*)   (ws + 134217728);     // 4096*64*4    = 1 MiB
    float*    sd    = (float*)   (ws + 135266304);     // 16 KiB
    float*    scale = (float*)   (ws + 135282688);     // 16 KiB
    float*    poolT = (float*)   (ws + 135299072);     // 512 KiB
    float*    invA  = (float*)   (ws + 135823360);     // 16 KiB

    p1_prep<<<dim3(6464), dim3(256), 0, stream>>>(E, x, adj, pool, A, invA, Xtt, sd, scale, poolT);
    p2_fused<<<dim3(1792), dim3(256), 0, stream>>>(A, Xtt, invA, XG, E, adj, sd, poolT,
                                                   bias_pool, scale, Wt, biasn);
    k6_gconv<<<dim3(1024), dim3(256), 0, stream>>>(x, XG, Wt, biasn, scale, lin_w, lin_b, out);
}

// Round 7
// 338.180 us; speedup vs baseline: 1.8024x; 1.0015x over previous
//
#include <hip/hip_runtime.h>
#include <stdint.h>

// Problem dims
#define Bdim 32
#define Ndim 4096
#define Cin  64
#define Cout 64
#define Demb 16

typedef __bf16 bf16x8 __attribute__((ext_vector_type(8)));
typedef float  f32x4  __attribute__((ext_vector_type(4)));

#define GLOBAL_AS(p) ((__attribute__((address_space(1))) void*)(p))
#define LDS_AS(p)    ((__attribute__((address_space(3))) void*)(p))

__device__ __forceinline__ uint16_t f2bf(float x) {
    union { float f; uint32_t u; } v; v.f = x;
    uint32_t r = v.u + 0x7FFFu + ((v.u >> 16) & 1u);   // RNE, finite inputs
    return (uint16_t)(r >> 16);
}

__device__ __forceinline__ bf16x8 pack8(float4 a, float4 b) {
    union { uint16_t u[8]; bf16x8 v; } r;
    r.u[0] = f2bf(a.x); r.u[1] = f2bf(a.y); r.u[2] = f2bf(a.z); r.u[3] = f2bf(a.w);
    r.u[4] = f2bf(b.x); r.u[5] = f2bf(b.y); r.u[6] = f2bf(b.z); r.u[7] = f2bf(b.w);
    return r.v;
}

// ---------------------------------------------------------------------------
// P1: fused independent prep (blockIdx-partitioned roles, all 256-thread):
//   [0,256)      k1: A~[n][m] = bf16(exp(relu(E[n]·E[m]))) UNNORMALIZED,
//                    invA[n] = 1/rowsum  (normalization folded into k3)
//   [256,2304)   k2: Xtt[b*64+c][m] = bf16(x[b][m][c])  (LDS tile transpose)
//   [2304,6400)  k4a: sd[n] = rsqrt(rowsum(adj[n]) + 0.5); zero scale
//   [6400,6464)  k5a: poolT[d][o*128+ki] = pool[d][ki*64+o]
// ---------------------------------------------------------------------------
__global__ __launch_bounds__(256) void p1_prep(const float* __restrict__ E,
                                               const float* __restrict__ x,
                                               const float* __restrict__ adj,
                                               const float* __restrict__ pool,
                                               uint16_t* __restrict__ A,
                                               float* __restrict__ invA,
                                               uint16_t* __restrict__ Xtt,
                                               float* __restrict__ sd,
                                               float* __restrict__ scale,
                                               float* __restrict__ poolT) {
    __shared__ __align__(16) uint8_t smem[9232];
    const int t = threadIdx.x;
    const int blk = blockIdx.x;

    if (blk < 256) {
        // ---- k1: dynamic adjacency, one pass ----
        float* Er_s = (float*)smem;            // 16x16
        float* red_s = (float*)(smem + 1024);  // 4
        const int n0 = blk * 16;
        Er_s[t] = E[n0 * Demb + t];
        __syncthreads();
        for (int half = 0; half < 2; ++half) {
            float er[8][16];
#pragma unroll
            for (int r = 0; r < 8; ++r)
#pragma unroll
                for (int d = 0; d < 16; ++d) er[r][d] = Er_s[(half * 8 + r) * 16 + d];
            float sacc[8];
#pragma unroll
            for (int r = 0; r < 8; ++r) sacc[r] = 0.f;
            for (int c = 0; c < 16; ++c) {
                const int m = c * 256 + t;
                const float4* ep = (const float4*)(E + (size_t)m * Demb);
                float4 e0 = ep[0], e1 = ep[1], e2 = ep[2], e3 = ep[3];
                float em[16] = {e0.x, e0.y, e0.z, e0.w, e1.x, e1.y, e1.z, e1.w,
                                e2.x, e2.y, e2.z, e2.w, e3.x, e3.y, e3.z, e3.w};
#pragma unroll
                for (int r = 0; r < 8; ++r) {
                    float v = 0.f;
#pragma unroll
                    for (int d = 0; d < 16; ++d) v = fmaf(er[r][d], em[d], v);
                    v = fmaxf(v, 0.f);
                    const float e = __expf(v);
                    sacc[r] += e;
                    A[(size_t)(n0 + half * 8 + r) * Ndim + m] = f2bf(e);
                }
            }
#pragma unroll
            for (int r = 0; r < 8; ++r) {
                float s = sacc[r];
#pragma unroll
                for (int off = 32; off > 0; off >>= 1) s += __shfl_down(s, off, 64);
                __syncthreads();
                if ((t & 63) == 0) red_s[t >> 6] = s;
                __syncthreads();
                if (t == 0)
                    invA[n0 + half * 8 + r] = 1.f / (red_s[0] + red_s[1] + red_s[2] + red_s[3]);
            }
            __syncthreads();
        }
    } else if (blk < 2304) {
        // ---- k2: x transpose to Xtt ----
        auto T = (uint16_t(*)[72])smem;
        const int idx = blk - 256;
        const int m0 = (idx & 63) * 64;
        const int b = idx >> 6;
        const int c = t & 63;
#pragma unroll
        for (int j = 0; j < 16; ++j) {
            const int m = (t >> 6) + j * 4;
            T[c][m] = f2bf(x[((size_t)b * Ndim + (m0 + m)) * Cin + c]);
        }
        __syncthreads();
        const int c2 = t >> 2, mo = (t & 3) * 16;
        const uint4* src = (const uint4*)&T[c2][mo];
        uint4 v0 = src[0], v1 = src[1];
        uint4* dst = (uint4*)(Xtt + (size_t)(b * Cin + c2) * Ndim + m0 + mo);
        dst[0] = v0;
        dst[1] = v1;
    } else if (blk < 6400) {
        // ---- k4a: adj rowsum -> sd; zero scale ----
        float* red_s = (float*)smem;
        const int n = blk - 2304;
        if (n < 16) scale[n * 256 + t] = 0.f;
        const float4* ap = (const float4*)(adj + (size_t)n * Ndim);
        float s = 0.f;
#pragma unroll
        for (int q = 0; q < 4; ++q) {
            float4 a = ap[q * 256 + t];
            s += a.x + a.y + a.z + a.w;
        }
#pragma unroll
        for (int off = 32; off > 0; off >>= 1) s += __shfl_down(s, off, 64);
        if ((t & 63) == 0) red_s[t >> 6] = s;
        __syncthreads();
        if (t == 0) sd[n] = sqrtf(1.f / (red_s[0] + red_s[1] + red_s[2] + red_s[3] + 0.5f));
    } else {
        // ---- k5a: pool transpose ----
        const int idx = blk - 6400;
        const int d = idx >> 2;
        const int base = (idx & 3) * 2048;
#pragma unroll
        for (int j = 0; j < 8; ++j) {
            const int e = base + j * 256 + t;          // e = ki*64 + o
            const float v = pool[d * 8192 + e];
            poolT[d * 8192 + (e & 63) * 128 + (e >> 6)] = v;
        }
    }
}

// ---------------------------------------------------------------------------
// P2: k4b (wave-restructured) + k5b, separate launch so k3 keeps its CUs.
//   [0,256)     k4b: scale[m] += colsum(rowsoftmax(rowsoftmax(sym-norm adj)))
//               Wave owns 4 full rows; softmax sums via shfl_xor allreduce
//               (zero barriers in hot loop); colsum combined via LDS atomics.
//               Max pass dropped: exp args bounded ~[0,4], shift-invariant.
//   [256,1280)  k5b: Wt[n][o*128+ki] = bf16(sum_d E[n,d]*poolT[d][...]); biasn
// ---------------------------------------------------------------------------
__global__ __launch_bounds__(256) void p2_mid(const float* __restrict__ E,
                                              const float* __restrict__ adj,
                                              const float* __restrict__ sd,
                                              const float* __restrict__ poolT,
                                              const float* __restrict__ bias_pool,
                                              float* __restrict__ scale,
                                              uint16_t* __restrict__ Wt,
                                              float* __restrict__ biasn) {
    __shared__ __align__(16) uint8_t smem[16384];
    const int t = threadIdx.x;
    const int blk = blockIdx.x;

    if (blk < 256) {
        // ---- k4b (wave-owned rows) ----
        float* cs = (float*)smem;                     // colsum accumulator [4096]
#pragma unroll
        for (int i = 0; i < 16; ++i) cs[i * 256 + t] = 0.f;
        __syncthreads();

        const int wv = t >> 6, l = t & 63;
        const int nb = blk * 16 + wv * 4;

        float sdm[64];
#pragma unroll
        for (int i = 0; i < 16; ++i) {
            float4 s4 = *(const float4*)(sd + i * 256 + l * 4);
            sdm[i * 4 + 0] = s4.x; sdm[i * 4 + 1] = s4.y;
            sdm[i * 4 + 2] = s4.z; sdm[i * 4 + 3] = s4.w;
        }
        float colsum[64];
#pragma unroll
        for (int k = 0; k < 64; ++k) colsum[k] = 0.f;

        for (int r = 0; r < 4; ++r) {
            const int n = nb + r;
            const float sdn = sd[n];
            float e1[64];
            float s1 = 0.f;
#pragma unroll
            for (int i = 0; i < 16; ++i) {
                float4 a4 = *(const float4*)(adj + (size_t)n * Ndim + i * 256 + l * 4);
                const int c0 = i * 256 + l * 4;
                float vv[4] = {a4.x, a4.y, a4.z, a4.w};
#pragma unroll
                for (int u = 0; u < 4; ++u) {
                    const float vd = vv[u] + ((c0 + u) == n ? 0.5f : 0.f);
                    const float e = __expf(sdn * vd * sdm[i * 4 + u]);
                    e1[i * 4 + u] = e;
                    s1 += e;
                }
            }
#pragma unroll
            for (int off = 32; off > 0; off >>= 1) s1 += __shfl_xor(s1, off, 64);
            const float inv1 = 1.f / s1;
            float s2 = 0.f;
#pragma unroll
            for (int k = 0; k < 64; ++k) {
                const float e = __expf(e1[k] * inv1);
                e1[k] = e;
                s2 += e;
            }
#pragma unroll
            for (int off = 32; off > 0; off >>= 1) s2 += __shfl_xor(s2, off, 64);
            const float inv2 = 1.f / s2;
#pragma unroll
            for (int k = 0; k < 64; ++k) colsum[k] = fmaf(e1[k], inv2, colsum[k]);
        }
        // combine waves in LDS, then one global-atomic pass
#pragma unroll
        for (int k = 0; k < 64; ++k)
            atomicAdd(&cs[(k >> 2) * 256 + l * 4 + (k & 3)], colsum[k]);
        __syncthreads();
#pragma unroll
        for (int i = 0; i < 16; ++i)
            atomicAdd(scale + i * 256 + t, cs[i * 256 + t]);
    } else {
        // ---- k5b ----
        float* En = (float*)smem;   // 32x16
        const int idx = blk - 256;
        const int ec = idx & 7;
        const int n0 = (idx >> 3) * 32;
        En[t] = E[n0 * Demb + t];
        En[t + 256] = E[n0 * Demb + t + 256];
        __syncthreads();

        const int e0 = ec * 1024 + t * 4;
        float4 P[16];
#pragma unroll
        for (int d = 0; d < 16; ++d) P[d] = *(const float4*)(poolT + d * 8192 + e0);

        for (int g = 0; g < 32; ++g) {
            float4 acc = {0.f, 0.f, 0.f, 0.f};
#pragma unroll
            for (int d = 0; d < 16; ++d) {
                const float e = En[g * 16 + d];
                acc.x = fmaf(e, P[d].x, acc.x);
                acc.y = fmaf(e, P[d].y, acc.y);
                acc.z = fmaf(e, P[d].z, acc.z);
                acc.w = fmaf(e, P[d].w, acc.w);
            }
            union { uint16_t u[4]; uint2 v; } r;
            r.u[0] = f2bf(acc.x); r.u[1] = f2bf(acc.y);
            r.u[2] = f2bf(acc.z); r.u[3] = f2bf(acc.w);
            *(uint2*)(Wt + (size_t)(n0 + g) * 8192 + e0) = r.v;
        }

        if (ec == 0) {
            const int o = t & 63, gq = t >> 6;
#pragma unroll
            for (int gi = 0; gi < 8; ++gi) {
                const int g = gi * 4 + gq;
                float a = 0.f;
#pragma unroll
                for (int d = 0; d < 16; ++d) a = fmaf(En[g * 16 + d], bias_pool[d * 64 + o], a);
                biasn[(size_t)(n0 + g) * 64 + o] = a;
            }
        }
    }
}

// ---------------------------------------------------------------------------
// K3: XG[n][j] = invA[n] * sum_m A~[n][m] * Xtt[j][m]  (4096 x 2048 x 4096)
// Standalone launch (512 blocks = 2/CU) — co-residency with k4b/k5b measured
// to dilute MfmaUtil 31% -> 18% (R6).  m97-style 128x128 tile, BK=32,
// global_load_lds w=16, XOR chunk swizzle; invA folded into epilogue.
// ---------------------------------------------------------------------------
#define GK 4096
#define GN 2048
__global__ __launch_bounds__(256) void k3_gemm(const uint16_t* __restrict__ Abf,
                                               const uint16_t* __restrict__ Bbf,
                                               const float* __restrict__ invA,
                                               uint16_t* __restrict__ Cbf) {
    __shared__ __align__(16) uint16_t As[128 * 32];
    __shared__ __align__(16) uint16_t Bs[128 * 32];
    const int t = threadIdx.x;
    const int lane = t & 63;
    const int w = t >> 6;
    const int wr = w >> 1, wc = w & 1;
    const int bm = blockIdx.y * 128;
    const int bn = blockIdx.x * 128;

    f32x4 acc[4][4];
#pragma unroll
    for (int i = 0; i < 4; ++i)
#pragma unroll
        for (int j = 0; j < 4; ++j) acc[i][j] = (f32x4){0.f, 0.f, 0.f, 0.f};

    const uint16_t* agp[2];
    const uint16_t* bgp[2];
    uint16_t* alp[2];
    uint16_t* blp[2];
#pragma unroll
    for (int i = 0; i < 2; ++i) {
        const int r = w * 32 + i * 16 + (lane >> 2);
        const int cg = (lane & 3) ^ ((r >> 1) & 3);
        agp[i] = Abf + (size_t)(bm + r) * GK + cg * 8;
        bgp[i] = Bbf + (size_t)(bn + r) * GK + cg * 8;
        alp[i] = &As[(w * 32 + i * 16) * 32];
        blp[i] = &Bs[(w * 32 + i * 16) * 32];
    }

    int offA[4], offB[4];
#pragma unroll
    for (int i = 0; i < 4; ++i) {
        const int m = wr * 64 + i * 16 + (lane & 15);
        offA[i] = m * 32 + (((lane >> 4) ^ ((m >> 1) & 3)) * 8);
        const int n = wc * 64 + i * 16 + (lane & 15);
        offB[i] = n * 32 + (((lane >> 4) ^ ((n >> 1) & 3)) * 8);
    }

    for (int kt = 0; kt < GK / 32; ++kt) {
#pragma unroll
        for (int i = 0; i < 2; ++i) {
            __builtin_amdgcn_global_load_lds(GLOBAL_AS(agp[i] + (size_t)kt * 32), LDS_AS(alp[i]), 16, 0, 0);
            __builtin_amdgcn_global_load_lds(GLOBAL_AS(bgp[i] + (size_t)kt * 32), LDS_AS(blp[i]), 16, 0, 0);
        }
        __syncthreads();
        bf16x8 af[4], bfr[4];
#pragma unroll
        for (int i = 0; i < 4; ++i) {
            af[i] = *(const bf16x8*)(As + offA[i]);
            bfr[i] = *(const bf16x8*)(Bs + offB[i]);
        }
#pragma unroll
        for (int i = 0; i < 4; ++i)
#pragma unroll
            for (int j = 0; j < 4; ++j)
                acc[i][j] = __builtin_amdgcn_mfma_f32_16x16x32_bf16(af[i], bfr[j], acc[i][j], 0, 0, 0);
        __syncthreads();
    }
#pragma unroll
    for (int i = 0; i < 4; ++i) {
        float invv[4];
#pragma unroll
        for (int r = 0; r < 4; ++r)
            invv[r] = invA[bm + wr * 64 + i * 16 + (lane >> 4) * 4 + r];
#pragma unroll
        for (int j = 0; j < 4; ++j)
#pragma unroll
            for (int r = 0; r < 4; ++r) {
                const int row = bm + wr * 64 + i * 16 + (lane >> 4) * 4 + r;
                const int col = bn + wc * 64 + j * 16 + (lane & 15);
                Cbf[(size_t)row * GN + col] = f2bf(acc[i][j][r] * invv[r]);
            }
    }
}

// ---------------------------------------------------------------------------
// K6 (MFMA, no W staging): one wave per node n.  B-fragments of Wt load
// DIRECTLY from global (each element consumed exactly once).
// LDS = lin_w image only -> one barrier, high occupancy.
// ---------------------------------------------------------------------------
__global__ __launch_bounds__(256) void k6_gconv(const float* __restrict__ x,
                                                const uint16_t* __restrict__ XG,
                                                const uint16_t* __restrict__ Wt,
                                                const float* __restrict__ biasn,
                                                const float* __restrict__ scale,
                                                const float* __restrict__ lin_w,
                                                const float* __restrict__ lin_b,
                                                float* __restrict__ out) {
    __shared__ __align__(16) uint16_t Lws[64][72];
    const int t = threadIdx.x;
    const int n0 = blockIdx.x * 4;

    {
        const int o = t >> 2, i0 = (t & 3) * 16;
        const float4* lp = (const float4*)(lin_w + o * 64 + i0);
        float4 a0 = lp[0], a1 = lp[1], a2 = lp[2], a3 = lp[3];
        union { uint16_t u[16]; uint4 v[2]; } r;
        r.u[0] = f2bf(a0.x); r.u[1] = f2bf(a0.y); r.u[2]  = f2bf(a0.z); r.u[3]  = f2bf(a0.w);
        r.u[4] = f2bf(a1.x); r.u[5] = f2bf(a1.y); r.u[6]  = f2bf(a1.z); r.u[7]  = f2bf(a1.w);
        r.u[8] = f2bf(a2.x); r.u[9] = f2bf(a2.y); r.u[10] = f2bf(a2.z); r.u[11] = f2bf(a2.w);
        r.u[12] = f2bf(a3.x); r.u[13] = f2bf(a3.y); r.u[14] = f2bf(a3.z); r.u[15] = f2bf(a3.w);
        *(uint4*)&Lws[o][i0] = r.v[0];
        *(uint4*)&Lws[o][i0 + 8] = r.v[1];
    }

    const int w = t >> 6, lane = t & 63;
    const int n = n0 + w;
    const int l15 = lane & 15;
    const int q8 = (lane >> 4) * 8;

    bf16x8 a[2][4];
#pragma unroll
    for (int mt = 0; mt < 2; ++mt) {
        const int b = mt * 16 + l15;
        const float* xp = x + ((size_t)b * Ndim + n) * 64 + q8;
        a[mt][0] = pack8(((const float4*)xp)[0], ((const float4*)xp)[1]);
        a[mt][1] = pack8(((const float4*)(xp + 32))[0], ((const float4*)(xp + 32))[1]);
        const uint16_t* gp = XG + (size_t)n * 2048 + b * 64 + q8;
        a[mt][2] = *(const bf16x8*)gp;
        a[mt][3] = *(const bf16x8*)(gp + 32);
    }

    f32x4 accg[2][4], accs[2][4];
#pragma unroll
    for (int mt = 0; mt < 2; ++mt)
#pragma unroll
        for (int j = 0; j < 4; ++j) {
            accg[mt][j] = (f32x4){0.f, 0.f, 0.f, 0.f};
            accs[mt][j] = (f32x4){0.f, 0.f, 0.f, 0.f};
        }

    const uint16_t* wp = Wt + (size_t)n * 8192 + l15 * 128 + q8;

    __syncthreads();   // Lws ready

#pragma unroll
    for (int ks = 0; ks < 4; ++ks) {
        bf16x8 bw[4];
#pragma unroll
        for (int j = 0; j < 4; ++j)
            bw[j] = *(const bf16x8*)(wp + j * 2048 + ks * 32);
#pragma unroll
        for (int mt = 0; mt < 2; ++mt)
#pragma unroll
            for (int j = 0; j < 4; ++j)
                accg[mt][j] = __builtin_amdgcn_mfma_f32_16x16x32_bf16(a[mt][ks], bw[j], accg[mt][j], 0, 0, 0);
        if (ks < 2) {
            bf16x8 bl[4];
#pragma unroll
            for (int j = 0; j < 4; ++j)
                bl[j] = *(const bf16x8*)&Lws[j * 16 + l15][ks * 32 + q8];
#pragma unroll
            for (int mt = 0; mt < 2; ++mt)
#pragma unroll
                for (int j = 0; j < 4; ++j)
                    accs[mt][j] = __builtin_amdgcn_mfma_f32_16x16x32_bf16(a[mt][ks], bl[j], accs[mt][j], 0, 0, 0);
        }
    }

    const float sc = scale[n];
#pragma unroll
    for (int j = 0; j < 4; ++j) {
        const int o = j * 16 + l15;
        const float bn = biasn[(size_t)n * 64 + o];
        const float lb = lin_b[o];
#pragma unroll
        for (int mt = 0; mt < 2; ++mt)
#pragma unroll
            for (int r = 0; r < 4; ++r) {
                const int b = mt * 16 + (lane >> 4) * 4 + r;
                const float gg = accg[mt][j][r] + bn;
                const float xs = sc * accs[mt][j][r] + lb;
                out[((size_t)b * Ndim + n) * 64 + o] = gg + xs / (1.f + __expf(-xs));
            }
    }
}

// ---------------------------------------------------------------------------
extern "C" void kernel_launch(void* const* d_in, const int* in_sizes, int n_in,
                              void* d_out, int out_size, void* d_ws, size_t ws_size,
                              hipStream_t stream) {
    const float* x         = (const float*)d_in[0];
    const float* E         = (const float*)d_in[1];
    const float* pool      = (const float*)d_in[2];
    const float* bias_pool = (const float*)d_in[3];
    const float* lin_w     = (const float*)d_in[4];
    const float* lin_b     = (const float*)d_in[5];
    const float* adj       = (const float*)d_in[6];
    float* out = (float*)d_out;

    uint8_t* ws = (uint8_t*)d_ws;
    uint16_t* A     = (uint16_t*)(ws);                 // 4096*4096*2  = 32 MiB
    uint16_t* Xtt   = (uint16_t*)(ws + 33554432);      // 2048*4096*2  = 16 MiB
    uint16_t* XG    = (uint16_t*)(ws + 50331648);      // 4096*2048*2  = 16 MiB
    uint16_t* Wt    = (uint16_t*)(ws + 67108864);      // 4096*8192*2  = 64 MiB
    float*    biasn = (float*)   (ws + 134217728);     // 4096*64*4    = 1 MiB
    float*    sd    = (float*)   (ws + 135266304);     // 16 KiB
    float*    scale = (float*)   (ws + 135282688);     // 16 KiB
    float*    poolT = (float*)   (ws + 135299072);     // 512 KiB
    float*    invA  = (float*)   (ws + 135823360);     // 16 KiB

    p1_prep<<<dim3(6464), dim3(256), 0, stream>>>(E, x, adj, pool, A, invA, Xtt, sd, scale, poolT);
    p2_mid<<<dim3(1280), dim3(256), 0, stream>>>(E, adj, sd, poolT, bias_pool, scale, Wt, biasn);
    k3_gemm<<<dim3(16, 32), dim3(256), 0, stream>>>(A, Xtt, invA, XG);
    k6_gconv<<<dim3(1024), dim3(256), 0, stream>>>(x, XG, Wt, biasn, scale, lin_w, lin_b, out);
}